// Round 1
// baseline (778.644 us; speedup 1.0000x reference)
//
#include <hip/hip_runtime.h>

// ---------------------------------------------------------------------------
// FastSelfAttention on MI355X (gfx950), bf16 MFMA pipeline.
// B=8, S=4096, D=1024, H=16, DH=64. All inputs f32; internal GEMMs bf16.
// ---------------------------------------------------------------------------

typedef unsigned short u16;
typedef float f32x4 __attribute__((ext_vector_type(4)));
typedef short bf16x8 __attribute__((ext_vector_type(8)));

#define DEV __device__ __forceinline__

constexpr int Bc = 8, Sc = 4096, Dc = 1024, Hc = 16;
constexpr int Mc = Bc * Sc;  // 32768

DEV u16 f2bf(float f) {
  union { float f; unsigned u; } c; c.f = f;
  return (u16)((c.u + 0x7FFFu + ((c.u >> 16) & 1u)) >> 16);
}
DEV float bf2f(u16 h) {
  union { unsigned u; float f; } c; c.u = ((unsigned)h) << 16;
  return c.f;
}

// --- f32 -> bf16 bulk convert (vectorized, G13) ----------------------------
__global__ __launch_bounds__(256) void k_cvt(const float* __restrict__ in,
                                             u16* __restrict__ out, int n4) {
  int i = blockIdx.x * 256 + threadIdx.x;
  const int stride = gridDim.x * 256;
  for (; i < n4; i += stride) {
    float4 v = reinterpret_cast<const float4*>(in)[i];
    ushort4 o;
    o.x = f2bf(v.x); o.y = f2bf(v.y); o.z = f2bf(v.z); o.w = f2bf(v.w);
    reinterpret_cast<ushort4*>(out)[i] = o;
  }
}

// --- W (K,N) f32 -> W^T (N,K) bf16 -----------------------------------------
__global__ __launch_bounds__(256) void k_transw(const float* __restrict__ W,
                                                u16* __restrict__ Wt) {
  __shared__ float tile[32][33];
  const int bn = blockIdx.x, bk = blockIdx.y;
  const int tx = threadIdx.x & 31, ty = threadIdx.x >> 5;
#pragma unroll
  for (int j = 0; j < 4; ++j)
    tile[ty + j * 8][tx] = W[(size_t)(bk * 32 + ty + j * 8) * Dc + bn * 32 + tx];
  __syncthreads();
#pragma unroll
  for (int j = 0; j < 4; ++j)
    Wt[(size_t)(bn * 32 + ty + j * 8) * Dc + bk * 32 + tx] = f2bf(tile[tx][ty + j * 8]);
}

// --- Wcomb = Wq @ Wqa (1024x16), beff = bq@Wqa + bqa  (f32, atomics) -------
__global__ __launch_bounds__(256) void k_wcomb(const float* __restrict__ Wq,
                                               const float* __restrict__ Wqa,
                                               const float* __restrict__ bq,
                                               const float* __restrict__ bqa,
                                               float* __restrict__ Wcomb,
                                               float* __restrict__ beff) {
  const int tg = blockIdx.x * 256 + threadIdx.x;  // 131072 threads
  const int h = tg & 15;
  const int d = (tg >> 4) & 1023;
  const int kc = tg >> 14;  // 0..7
  const int j0 = kc * 128;
  float s = 0.f;
  for (int j = j0; j < j0 + 128; ++j)
    s += Wq[(size_t)d * 1024 + j] * Wqa[j * 16 + h];
  atomicAdd(&Wcomb[d * 16 + h], s);
  if (d == 0) {
    float bs = (kc == 0) ? bqa[h] : 0.f;
    for (int j = j0; j < j0 + 128; ++j) bs += bq[j] * Wqa[j * 16 + h];
    atomicAdd(&beff[h], bs);
  }
}

// --- main GEMM: C(MxN) = A(MxK,bf16) x Bt(NxK,bf16)^T, 128x128 tile --------
// EPI 0: Cf = acc + bias
// EPI 1: Cb = bf16((acc + bias) * extra[b, col])        (mixed_qk)
// EPI 2: Cf = acc + bias + extra[row, col]              (out = .. + q)
template <int EPI>
__global__ __launch_bounds__(256) void k_gemm(const u16* __restrict__ A,
                                              const u16* __restrict__ Bt,
                                              const float* __restrict__ bias,
                                              const float* __restrict__ extra,
                                              float* __restrict__ Cf,
                                              u16* __restrict__ Cb) {
  constexpr int K = Dc, N = Dc;
  __shared__ __align__(16) u16 lsA[128 * 32];
  __shared__ __align__(16) u16 lsB[128 * 32];
  const int tid = threadIdx.x;
  const int w = tid >> 6, l = tid & 63;
  const int row0 = blockIdx.y * 128, col0 = blockIdx.x * 128;
  const int wr = (w >> 1) * 64, wc = (w & 1) * 64;
  f32x4 acc[4][4] = {};

  for (int kt = 0; kt < K; kt += 32) {
    // stage A & B tiles (128x32 bf16 each) via async global->LDS, 16B/lane
#pragma unroll
    for (int i = 0; i < 2; ++i) {
      const int off = i * 4096 + tid * 16;       // byte offset in tile
      const int r = off >> 6, cb = off & 63;     // row, byte-in-row (64B rows)
      const u16* ga = A + (size_t)(row0 + r) * K + kt + (cb >> 1);
      const u16* gb = Bt + (size_t)(col0 + r) * K + kt + (cb >> 1);
      __builtin_amdgcn_global_load_lds(
          (const __attribute__((address_space(1))) void*)ga,
          (__attribute__((address_space(3))) void*)((char*)lsA + i * 4096 + w * 1024),
          16, 0, 0);
      __builtin_amdgcn_global_load_lds(
          (const __attribute__((address_space(1))) void*)gb,
          (__attribute__((address_space(3))) void*)((char*)lsB + i * 4096 + w * 1024),
          16, 0, 0);
    }
    __syncthreads();  // compiler drains vmcnt before barrier
    bf16x8 aF[4], bF[4];
#pragma unroll
    for (int m = 0; m < 4; ++m)
      aF[m] = *reinterpret_cast<const bf16x8*>(
          &lsA[(wr + m * 16 + (l & 15)) * 32 + (l >> 4) * 8]);
#pragma unroll
    for (int n = 0; n < 4; ++n)
      bF[n] = *reinterpret_cast<const bf16x8*>(
          &lsB[(wc + n * 16 + (l & 15)) * 32 + (l >> 4) * 8]);
#pragma unroll
    for (int m = 0; m < 4; ++m)
#pragma unroll
      for (int n = 0; n < 4; ++n)
        acc[m][n] = __builtin_amdgcn_mfma_f32_16x16x32_bf16(aF[m], bF[n], acc[m][n], 0, 0, 0);
    __syncthreads();
  }

  // epilogue: C/D layout col=lane&15, row=(lane>>4)*4+reg
  const int lr = (l >> 4) * 4, lc = l & 15;
#pragma unroll
  for (int n = 0; n < 4; ++n) {
    const int col = col0 + wc + n * 16 + lc;
    const float bv = bias[col];
#pragma unroll
    for (int m = 0; m < 4; ++m) {
      const int rb = row0 + wr + m * 16 + lr;
#pragma unroll
      for (int j = 0; j < 4; ++j) {
        const int row = rb + j;
        float v = acc[m][n][j] + bv;
        if constexpr (EPI == 0) {
          Cf[(size_t)row * N + col] = v;
        } else if constexpr (EPI == 1) {
          const int b = row >> 12;  // S=4096
          v *= extra[b * Dc + col];
          Cb[(size_t)row * N + col] = f2bf(v);
        } else {
          v += extra[(size_t)row * N + col];
          Cf[(size_t)row * N + col] = v;
        }
      }
    }
  }
}

// --- score: score[b,h,s] = (X[b,s,:]·Wa[:,h] + bias[h])*scale + mask[b,s] --
// X bf16 (M,1024); Wa f32 (1024,16). One wave handles 4 rows per pass.
__global__ __launch_bounds__(256) void k_score(const u16* __restrict__ X,
                                               const float* __restrict__ Wa,
                                               const float* __restrict__ bias,
                                               const float* __restrict__ mask,
                                               float* __restrict__ score,
                                               float scale) {
  __shared__ float waT[16][1024];  // [h][d], lane-consecutive d -> conflict-free
  for (int t = threadIdx.x; t < 16384; t += 256) waT[t & 15][t >> 4] = Wa[t];
  __syncthreads();
  const int w = threadIdx.x >> 6, l = threadIdx.x & 63;
  const int gstride = gridDim.x * 4;
  for (int g = blockIdx.x * 4 + w; g < Mc / 4; g += gstride) {
    const size_t r0 = (size_t)g * 4;
    float cur[64];  // idx = rr*16 + h
#pragma unroll
    for (int i = 0; i < 64; ++i) cur[i] = 0.f;
    for (int i = 0; i < 8; ++i) {
      const int d = i * 128 + l * 2;
      float x[4][2];
#pragma unroll
      for (int rr = 0; rr < 4; ++rr) {
        ushort2 xv = *reinterpret_cast<const ushort2*>(&X[(r0 + rr) * 1024 + d]);
        x[rr][0] = bf2f(xv.x); x[rr][1] = bf2f(xv.y);
      }
#pragma unroll
      for (int h = 0; h < 16; ++h) {
        float2 wv = *reinterpret_cast<const float2*>(&waT[h][d]);
#pragma unroll
        for (int rr = 0; rr < 4; ++rr)
          cur[rr * 16 + h] += x[rr][0] * wv.x + x[rr][1] * wv.y;
      }
    }
    // halving butterfly: after step s, lane holds 64>>(s+1) sums;
    // ends with lane l holding the full sum for idx = l.
#pragma unroll
    for (int s = 0; s < 6; ++s) {
      const int m = 1 << s;
      const int bit = (l >> s) & 1;
#pragma unroll
      for (int j = 0; j < (32 >> s); ++j) {
        const float mine = bit ? cur[2 * j + 1] : cur[2 * j];
        const float other = bit ? cur[2 * j] : cur[2 * j + 1];
        cur[j] = mine + __shfl_xor(other, m, 64);
      }
    }
    const int rr = l >> 4, h = l & 15;
    const size_t r = r0 + rr;
    const int b = (int)(r >> 12), si = (int)(r & 4095);
    score[((size_t)b * 16 + h) * 4096 + si] =
        (cur[0] + bias[h]) * scale + mask[b * 4096 + si];
  }
}

// --- softmax over S (in place), one block per (b,h) row --------------------
__global__ __launch_bounds__(256) void k_softmax(float* __restrict__ sc) {
  __shared__ float red[8];
  float* p = sc + (size_t)blockIdx.x * 4096;
  const int t = threadIdx.x, w = t >> 6, l = t & 63;
  float v[16];
  float mx = -3.0e38f;
#pragma unroll
  for (int i = 0; i < 16; ++i) { v[i] = p[t + i * 256]; mx = fmaxf(mx, v[i]); }
#pragma unroll
  for (int m = 1; m < 64; m <<= 1) mx = fmaxf(mx, __shfl_xor(mx, m, 64));
  if (l == 0) red[w] = mx;
  __syncthreads();
  mx = fmaxf(fmaxf(red[0], red[1]), fmaxf(red[2], red[3]));
  float sum = 0.f;
#pragma unroll
  for (int i = 0; i < 16; ++i) { v[i] = __expf(v[i] - mx); sum += v[i]; }
#pragma unroll
  for (int m = 1; m < 64; m <<= 1) sum += __shfl_xor(sum, m, 64);
  if (l == 0) red[4 + w] = sum;
  __syncthreads();
  const float inv = 1.f / (red[4] + red[5] + red[6] + red[7]);
#pragma unroll
  for (int i = 0; i < 16; ++i) p[t + i * 256] = v[i] * inv;
}

// --- pooled[b,d] = sum_s w[b, d>>6, s] * X[b,s,d]  (atomic over S-chunks) --
template <int IS_BF16>
__global__ __launch_bounds__(256) void k_pool(const float* __restrict__ wgt,
                                              const void* __restrict__ Xv,
                                              float* __restrict__ pooled) {
  __shared__ float wl[16][132];  // pad breaks bank aliasing
  const int b = blockIdx.x >> 5, c = blockIdx.x & 31;
  const int s0 = c * 128;
  for (int t = threadIdx.x; t < 2048; t += 256) {
    const int h = t >> 7, si = t & 127;
    wl[h][si] = wgt[((size_t)b * 16 + h) * 4096 + s0 + si];
  }
  __syncthreads();
  const int d0 = threadIdx.x * 4, h = threadIdx.x >> 4;
  float a0 = 0, a1 = 0, a2 = 0, a3 = 0;
  for (int si = 0; si < 128; ++si) {
    const float wv = wl[h][si];
    const size_t base = ((size_t)b * 4096 + s0 + si) * 1024 + d0;
    if constexpr (IS_BF16) {
      ushort4 xq = *reinterpret_cast<const ushort4*>((const u16*)Xv + base);
      a0 += wv * bf2f(xq.x); a1 += wv * bf2f(xq.y);
      a2 += wv * bf2f(xq.z); a3 += wv * bf2f(xq.w);
    } else {
      float4 xq = *reinterpret_cast<const float4*>((const float*)Xv + base);
      a0 += wv * xq.x; a1 += wv * xq.y; a2 += wv * xq.z; a3 += wv * xq.w;
    }
  }
  atomicAdd(&pooled[b * 1024 + d0 + 0], a0);
  atomicAdd(&pooled[b * 1024 + d0 + 1], a1);
  atomicAdd(&pooled[b * 1024 + d0 + 2], a2);
  atomicAdd(&pooled[b * 1024 + d0 + 3], a3);
}

// --- weighted[b,s,d] = pooled_k[b,d] * q[b,s,d]  -> bf16 -------------------
__global__ __launch_bounds__(256) void k_weighted(const float* __restrict__ q,
                                                  const float* __restrict__ pooled,
                                                  u16* __restrict__ outb) {
  int i = blockIdx.x * 256 + threadIdx.x;
  const int stride = gridDim.x * 256;
  for (; i < 8388608; i += stride) {
    const size_t e = (size_t)i * 4;
    const int d = (int)(e & 1023);
    const int b = (int)(e >> 22);  // S*D = 2^22
    float4 qv = *reinterpret_cast<const float4*>(q + e);
    float4 pv = *reinterpret_cast<const float4*>(pooled + b * 1024 + d);
    ushort4 o;
    o.x = f2bf(qv.x * pv.x); o.y = f2bf(qv.y * pv.y);
    o.z = f2bf(qv.z * pv.z); o.w = f2bf(qv.w * pv.w);
    *reinterpret_cast<ushort4*>(outb + e) = o;
  }
}

// ---------------------------------------------------------------------------
extern "C" void kernel_launch(void* const* d_in, const int* in_sizes, int n_in,
                              void* d_out, int out_size, void* d_ws, size_t ws_size,
                              hipStream_t stream) {
  (void)in_sizes; (void)n_in; (void)out_size; (void)ws_size;
  const float* x    = (const float*)d_in[0];
  const float* mask = (const float*)d_in[1];
  const float* Wq   = (const float*)d_in[2];
  const float* bq   = (const float*)d_in[3];
  const float* Wqa  = (const float*)d_in[4];
  const float* bqa  = (const float*)d_in[5];
  const float* Wk   = (const float*)d_in[6];
  const float* bk   = (const float*)d_in[7];
  const float* Wka  = (const float*)d_in[8];
  const float* bka  = (const float*)d_in[9];
  const float* Wt   = (const float*)d_in[10];
  const float* bt   = (const float*)d_in[11];
  float* out = (float*)d_out;
  char* ws = (char*)d_ws;

  size_t off = 0;
  auto take = [&](size_t b) { char* p = ws + off; off += (b + 255) & ~(size_t)255; return p; };
  u16*   xb    = (u16*)  take(67108864);    // x bf16; reused for `weighted` later
  float* q     = (float*)take(134217728);   // q f32 (needed exact-ish at the end)
  u16*   mixed = (u16*)  take(67108864);    // mixed_qk bf16
  u16*   Wqt   = (u16*)  take(2097152);
  u16*   Wkt   = (u16*)  take(2097152);
  u16*   Wtt   = (u16*)  take(2097152);
  float* Wcomb = (float*)take(65536);       // Wq@Wqa (1024,16)
  float* beff  = (float*)take(256);
  float* sc    = (float*)take(2097152);     // (B,H,S), reused q-path then k-path
  float* pq    = (float*)take(32768);       // pooled_q (B,1024)
  float* pk    = (float*)take(32768);       // pooled_k (B,1024)

  // prep
  k_cvt<<<2048, 256, 0, stream>>>(x, xb, 8388608);
  k_transw<<<dim3(32, 32), 256, 0, stream>>>(Wq, Wqt);
  k_transw<<<dim3(32, 32), 256, 0, stream>>>(Wk, Wkt);
  k_transw<<<dim3(32, 32), 256, 0, stream>>>(Wt, Wtt);
  hipMemsetAsync(Wcomb, 0, 65536, stream);
  hipMemsetAsync(beff, 0, 256, stream);
  k_wcomb<<<512, 256, 0, stream>>>(Wq, Wqa, bq, bqa, Wcomb, beff);

  // q path
  k_gemm<0><<<dim3(8, 256), 256, 0, stream>>>(xb, Wqt, bq, nullptr, q, nullptr);
  k_score<<<2048, 256, 0, stream>>>(xb, Wcomb, beff, mask, sc, 0.125f);
  k_softmax<<<128, 256, 0, stream>>>(sc);
  hipMemsetAsync(pq, 0, 32768, stream);
  k_pool<0><<<256, 256, 0, stream>>>(sc, q, pq);

  // k path (mixed_qk fused into GEMM epilogue)
  k_gemm<1><<<dim3(8, 256), 256, 0, stream>>>(xb, Wkt, bk, pq, nullptr, mixed);
  k_score<<<2048, 256, 0, stream>>>(mixed, Wka, bka, mask, sc, 0.125f);
  k_softmax<<<128, 256, 0, stream>>>(sc);
  hipMemsetAsync(pk, 0, 32768, stream);
  k_pool<1><<<256, 256, 0, stream>>>(sc, mixed, pk);

  // output path
  u16* wtd = xb;  // reuse (x no longer needed)
  k_weighted<<<2048, 256, 0, stream>>>(q, pk, wtd);
  k_gemm<2><<<dim3(8, 256), 256, 0, stream>>>(wtd, Wtt, bt, q, out, nullptr);
}

// Round 2
// 609.998 us; speedup vs baseline: 1.2765x; 1.2765x over previous
//
#include <hip/hip_runtime.h>

// ---------------------------------------------------------------------------
// FastSelfAttention on MI355X (gfx950), bf16 MFMA pipeline, round 2.
// B=8, S=4096, D=1024, H=16, DH=64.
// Key round-2 changes: fused q/k GEMM (N=2048), mixed_qk eliminated via
// (k . pq) @ Wka == k @ (pq . Wka) factorization, BK=64 swizzled LDS GEMM,
// chunked XCD block swizzle, q stored bf16.
// ---------------------------------------------------------------------------

typedef unsigned short u16;
typedef float f32x4 __attribute__((ext_vector_type(4)));
typedef short bf16x8 __attribute__((ext_vector_type(8)));

#define DEV __device__ __forceinline__

DEV u16 f2bf(float f) {
  union { float f; unsigned u; } c; c.f = f;
  return (u16)((c.u + 0x7FFFu + ((c.u >> 16) & 1u)) >> 16);
}
DEV float bf2f(u16 h) {
  union { unsigned u; float f; } c; c.u = ((unsigned)h) << 16;
  return c.f;
}

// --- f32 -> bf16 bulk convert ----------------------------------------------
__global__ __launch_bounds__(256) void k_cvt(const float* __restrict__ in,
                                             u16* __restrict__ out, int n4) {
  int i = blockIdx.x * 256 + threadIdx.x;
  const int stride = gridDim.x * 256;
  for (; i < n4; i += stride) {
    float4 v = reinterpret_cast<const float4*>(in)[i];
    ushort4 o;
    o.x = f2bf(v.x); o.y = f2bf(v.y); o.z = f2bf(v.z); o.w = f2bf(v.w);
    reinterpret_cast<ushort4*>(out)[i] = o;
  }
}

// --- W (K,N) f32 -> W^T (N,K) bf16 -----------------------------------------
__global__ __launch_bounds__(256) void k_transw(const float* __restrict__ W,
                                                u16* __restrict__ Wt) {
  __shared__ float tile[32][33];
  const int bn = blockIdx.x, bk = blockIdx.y;
  const int tx = threadIdx.x & 31, ty = threadIdx.x >> 5;
#pragma unroll
  for (int j = 0; j < 4; ++j)
    tile[ty + j * 8][tx] = W[(size_t)(bk * 32 + ty + j * 8) * 1024 + bn * 32 + tx];
  __syncthreads();
#pragma unroll
  for (int j = 0; j < 4; ++j)
    Wt[(size_t)(bn * 32 + ty + j * 8) * 1024 + bk * 32 + tx] = f2bf(tile[tx][ty + j * 8]);
}

// --- GEMM: C(M x gcols*128) = A(Mx1024 bf16) x Bt(N x 1024 bf16)^T ---------
// 128x128 tile, BK=64, XOR-swizzled LDS (phys_slot = log_slot ^ (row&7)),
// chunked XCD blockIdx swizzle (col-fastest within chunk for A-panel reuse).
// EPI 0: bf16 out, split into C0 (col<1024) / C1 (col>=1024), bias0/bias1.
// EPI 2: f32 out = acc + bias0[col] + bf2f(extra[row,col]).
template <int EPI>
__global__ __launch_bounds__(256) void k_gemm(const u16* __restrict__ A,
                                              const u16* __restrict__ Bt,
                                              const float* __restrict__ bias0,
                                              const float* __restrict__ bias1,
                                              const u16* __restrict__ extra,
                                              float* __restrict__ Cf,
                                              u16* __restrict__ C0,
                                              u16* __restrict__ C1,
                                              int gcols) {
  constexpr int K = 1024;
  __shared__ __align__(16) u16 lsA[128 * 64];
  __shared__ __align__(16) u16 lsB[128 * 64];
  const int tid = threadIdx.x, w = tid >> 6, l = tid & 63;

  // chunked XCD swizzle (nwg % 8 == 0 guaranteed by launch)
  const int nwg = gridDim.x;
  const int swz = (blockIdx.x & 7) * (nwg >> 3) + (blockIdx.x >> 3);
  const int ci = swz % gcols, ri = swz / gcols;
  const int row0 = ri * 128, col0 = ci * 128;
  const int wr = (w >> 1) * 64, wc = (w & 1) * 64;

  // staging source (pre-swizzled so linear LDS dest ends up XOR-swizzled):
  // dest byte L = p*4096 + tid*16 -> row = p*32 + (tid>>3), slot = tid&7;
  // phys slot `slot` holds logical slot (slot ^ (row&7)).
  const int srow = tid >> 3;
  const int lslot = (tid & 7) ^ (srow & 7);
  const u16* gA = A + (size_t)(row0 + srow) * K + lslot * 8;
  const u16* gB = Bt + (size_t)(col0 + srow) * K + lslot * 8;
  char* dA = (char*)lsA + w * 1024;
  char* dB = (char*)lsB + w * 1024;

  f32x4 acc[4][4] = {};
  const int lr15 = l & 15, lhi = l >> 4;

  for (int kt = 0; kt < K; kt += 64) {
#pragma unroll
    for (int p = 0; p < 4; ++p) {
      __builtin_amdgcn_global_load_lds(
          (const __attribute__((address_space(1))) void*)(gA + (size_t)p * 32 * K + kt),
          (__attribute__((address_space(3))) void*)(dA + p * 4096), 16, 0, 0);
      __builtin_amdgcn_global_load_lds(
          (const __attribute__((address_space(1))) void*)(gB + (size_t)p * 32 * K + kt),
          (__attribute__((address_space(3))) void*)(dB + p * 4096), 16, 0, 0);
    }
    __syncthreads();  // compiler drains vmcnt before barrier
#pragma unroll
    for (int ks = 0; ks < 2; ++ks) {
      bf16x8 aF[4], bF[4];
      const int phys = (ks * 4 + lhi) ^ (l & 7);  // row&7 == l&7 for our rows
#pragma unroll
      for (int m = 0; m < 4; ++m)
        aF[m] = *reinterpret_cast<const bf16x8*>(
            &lsA[(wr + m * 16 + lr15) * 64 + phys * 8]);
#pragma unroll
      for (int n = 0; n < 4; ++n)
        bF[n] = *reinterpret_cast<const bf16x8*>(
            &lsB[(wc + n * 16 + lr15) * 64 + phys * 8]);
#pragma unroll
      for (int m = 0; m < 4; ++m)
#pragma unroll
        for (int n = 0; n < 4; ++n)
          acc[m][n] = __builtin_amdgcn_mfma_f32_16x16x32_bf16(aF[m], bF[n], acc[m][n], 0, 0, 0);
    }
    __syncthreads();
  }

  // epilogue: C/D layout col=lane&15, row=(lane>>4)*4+reg
  const int lr = lhi * 4, lc = lr15;
#pragma unroll
  for (int n = 0; n < 4; ++n) {
    const int col = col0 + wc + n * 16 + lc;
    const float bv = (EPI == 0) ? (col < 1024 ? bias0[col] : bias1[col - 1024])
                                : bias0[col];
#pragma unroll
    for (int m = 0; m < 4; ++m) {
      const int rb = row0 + wr + m * 16 + lr;
#pragma unroll
      for (int j = 0; j < 4; ++j) {
        const int row = rb + j;
        const float v = acc[m][n][j] + bv;
        if constexpr (EPI == 0) {
          if (col < 1024) C0[(size_t)row * 1024 + col] = f2bf(v);
          else            C1[(size_t)row * 1024 + col - 1024] = f2bf(v);
        } else {
          const size_t idx = (size_t)row * 1024 + col;
          Cf[idx] = v + bf2f(extra[idx]);
        }
      }
    }
  }
}

// --- score[b,h,s] = (X[b,s,:].Weff[:,h] + bias[h])*scale + mask[b,s] -------
// Weff[d,h] = Wa[d,h] * (HAS_PQ ? pq[b,d] : 1).  X bf16. blockIdx.y = batch.
template <int HAS_PQ>
__global__ __launch_bounds__(256) void k_score(const u16* __restrict__ X,
                                               const float* __restrict__ Wa,
                                               const float* __restrict__ bias,
                                               const float* __restrict__ mask,
                                               const float* __restrict__ pq,
                                               float* __restrict__ score,
                                               float scale) {
  __shared__ float waT[16][1024];  // [h][d]
  const int b = blockIdx.y;
  for (int t = threadIdx.x; t < 16384; t += 256) {
    const int d = t >> 4, h = t & 15;
    float wv = Wa[t];
    if (HAS_PQ) wv *= pq[b * 1024 + d];
    waT[h][d] = wv;
  }
  __syncthreads();
  const int w = threadIdx.x >> 6, l = threadIdx.x & 63;
  for (int g = blockIdx.x * 4 + w; g < 1024; g += gridDim.x * 4) {
    const size_t r0 = (size_t)b * 4096 + g * 4;
    float cur[64];  // idx = rr*16 + h
#pragma unroll
    for (int i = 0; i < 64; ++i) cur[i] = 0.f;
    for (int i = 0; i < 8; ++i) {
      const int d = i * 128 + l * 2;
      float xv[4][2];
#pragma unroll
      for (int rr = 0; rr < 4; ++rr) {
        ushort2 xq = *reinterpret_cast<const ushort2*>(&X[(r0 + rr) * 1024 + d]);
        xv[rr][0] = bf2f(xq.x); xv[rr][1] = bf2f(xq.y);
      }
#pragma unroll
      for (int h = 0; h < 16; ++h) {
        float2 wv = *reinterpret_cast<const float2*>(&waT[h][d]);
#pragma unroll
        for (int rr = 0; rr < 4; ++rr)
          cur[rr * 16 + h] += xv[rr][0] * wv.x + xv[rr][1] * wv.y;
      }
    }
    // halving butterfly -> lane l ends with sum for idx=l (rr=l>>4, h=l&15)
#pragma unroll
    for (int s = 0; s < 6; ++s) {
      const int m = 1 << s;
      const int bit = (l >> s) & 1;
#pragma unroll
      for (int j = 0; j < (32 >> s); ++j) {
        const float mine = bit ? cur[2 * j + 1] : cur[2 * j];
        const float other = bit ? cur[2 * j] : cur[2 * j + 1];
        cur[j] = mine + __shfl_xor(other, m, 64);
      }
    }
    const int rr = l >> 4, h = l & 15;
    const int si = g * 4 + rr;
    score[((size_t)b * 16 + h) * 4096 + si] =
        (cur[0] + bias[h]) * scale + mask[b * 4096 + si];
  }
}

// --- softmax over S (in place), one block per (b,h) row --------------------
__global__ __launch_bounds__(256) void k_softmax(float* __restrict__ sc) {
  __shared__ float red[8];
  float* p = sc + (size_t)blockIdx.x * 4096;
  const int t = threadIdx.x, w = t >> 6, l = t & 63;
  float v[16];
  float mx = -3.0e38f;
#pragma unroll
  for (int i = 0; i < 16; ++i) { v[i] = p[t + i * 256]; mx = fmaxf(mx, v[i]); }
#pragma unroll
  for (int m = 1; m < 64; m <<= 1) mx = fmaxf(mx, __shfl_xor(mx, m, 64));
  if (l == 0) red[w] = mx;
  __syncthreads();
  mx = fmaxf(fmaxf(red[0], red[1]), fmaxf(red[2], red[3]));
  float sum = 0.f;
#pragma unroll
  for (int i = 0; i < 16; ++i) { v[i] = __expf(v[i] - mx); sum += v[i]; }
#pragma unroll
  for (int m = 1; m < 64; m <<= 1) sum += __shfl_xor(sum, m, 64);
  if (l == 0) red[4 + w] = sum;
  __syncthreads();
  const float inv = 1.f / (red[4] + red[5] + red[6] + red[7]);
#pragma unroll
  for (int i = 0; i < 16; ++i) p[t + i * 256] = v[i] * inv;
}

// --- pooled[b,d] = sum_s w[b, d>>6, s] * X[b,s,d]  (bf16 X, atomics) -------
__global__ __launch_bounds__(256) void k_pool(const float* __restrict__ wgt,
                                              const u16* __restrict__ X,
                                              float* __restrict__ pooled) {
  __shared__ float wl[16][132];
  const int b = blockIdx.x >> 5, c = blockIdx.x & 31;
  const int s0 = c * 128;
  for (int t = threadIdx.x; t < 2048; t += 256) {
    const int h = t >> 7, si = t & 127;
    wl[h][si] = wgt[((size_t)b * 16 + h) * 4096 + s0 + si];
  }
  __syncthreads();
  const int d0 = threadIdx.x * 4, h = threadIdx.x >> 4;
  float a0 = 0, a1 = 0, a2 = 0, a3 = 0;
  for (int si = 0; si < 128; ++si) {
    const float wv = wl[h][si];
    const size_t base = ((size_t)b * 4096 + s0 + si) * 1024 + d0;
    ushort4 xq = *reinterpret_cast<const ushort4*>(X + base);
    a0 += wv * bf2f(xq.x); a1 += wv * bf2f(xq.y);
    a2 += wv * bf2f(xq.z); a3 += wv * bf2f(xq.w);
  }
  atomicAdd(&pooled[b * 1024 + d0 + 0], a0);
  atomicAdd(&pooled[b * 1024 + d0 + 1], a1);
  atomicAdd(&pooled[b * 1024 + d0 + 2], a2);
  atomicAdd(&pooled[b * 1024 + d0 + 3], a3);
}

// --- wtd[b,s,d] = q_bf16[b,s,d] * pkraw[b,d] * pq[b,d]  -> bf16 ------------
__global__ __launch_bounds__(256) void k_weighted(const u16* __restrict__ qb,
                                                  const float* __restrict__ pkraw,
                                                  const float* __restrict__ pq,
                                                  u16* __restrict__ outb) {
  int i = blockIdx.x * 256 + threadIdx.x;
  const int stride = gridDim.x * 256;
  for (; i < 8388608; i += stride) {
    const size_t e = (size_t)i * 4;
    const int d = (int)(e & 1023);
    const int b = (int)(e >> 22);  // S*D = 2^22
    ushort4 qv = *reinterpret_cast<const ushort4*>(qb + e);
    float4 pkv = *reinterpret_cast<const float4*>(pkraw + b * 1024 + d);
    float4 pqv = *reinterpret_cast<const float4*>(pq + b * 1024 + d);
    ushort4 o;
    o.x = f2bf(bf2f(qv.x) * pkv.x * pqv.x);
    o.y = f2bf(bf2f(qv.y) * pkv.y * pqv.y);
    o.z = f2bf(bf2f(qv.z) * pkv.z * pqv.z);
    o.w = f2bf(bf2f(qv.w) * pkv.w * pqv.w);
    *reinterpret_cast<ushort4*>(outb + e) = o;
  }
}

// ---------------------------------------------------------------------------
extern "C" void kernel_launch(void* const* d_in, const int* in_sizes, int n_in,
                              void* d_out, int out_size, void* d_ws, size_t ws_size,
                              hipStream_t stream) {
  (void)in_sizes; (void)n_in; (void)out_size; (void)ws_size;
  const float* x    = (const float*)d_in[0];
  const float* mask = (const float*)d_in[1];
  const float* Wq   = (const float*)d_in[2];
  const float* bq   = (const float*)d_in[3];
  const float* Wqa  = (const float*)d_in[4];
  const float* bqa  = (const float*)d_in[5];
  const float* Wk   = (const float*)d_in[6];
  const float* bk   = (const float*)d_in[7];
  const float* Wka  = (const float*)d_in[8];
  const float* bka  = (const float*)d_in[9];
  const float* Wt   = (const float*)d_in[10];
  const float* bt   = (const float*)d_in[11];
  float* out = (float*)d_out;
  char* ws = (char*)d_ws;

  size_t off = 0;
  auto take = [&](size_t b) { char* p = ws + off; off += (b + 255) & ~(size_t)255; return p; };
  u16*   xb    = (u16*)  take(67108864);   // x bf16; reused as wtd later
  u16*   qb    = (u16*)  take(67108864);   // q bf16
  u16*   kb    = (u16*)  take(67108864);   // k bf16
  u16*   Wqkt  = (u16*)  take(4194304);    // [Wq^T ; Wk^T] (2048 x 1024) bf16
  u16*   Wtt   = (u16*)  take(2097152);    // Wt^T bf16
  float* sc    = (float*)take(2097152);    // (B,H,S) scores, reused q then k
  float* pq    = (float*)take(32768);      // pooled_q (B,1024) f32
  float* pk    = (float*)take(32768);      // raw pooled_k (B,1024) f32

  // prep
  k_cvt<<<2048, 256, 0, stream>>>(x, xb, 8388608);
  k_transw<<<dim3(32, 32), 256, 0, stream>>>(Wq, Wqkt);
  k_transw<<<dim3(32, 32), 256, 0, stream>>>(Wk, Wqkt + 1024 * 1024);
  k_transw<<<dim3(32, 32), 256, 0, stream>>>(Wt, Wtt);

  // fused q,k = x @ [Wq|Wk] + [bq|bk]   (grid: 16 col-tiles x 256 row-tiles)
  k_gemm<0><<<4096, 256, 0, stream>>>(xb, Wqkt, bq, bk, nullptr, nullptr, qb, kb, 16);

  // q path: score directly from q (q_score = (q@Wqa + bqa)*scale + mask)
  k_score<0><<<dim3(128, 8), 256, 0, stream>>>(qb, Wqa, bqa, mask, nullptr, sc, 0.125f);
  k_softmax<<<128, 256, 0, stream>>>(sc);
  hipMemsetAsync(pq, 0, 32768, stream);
  k_pool<<<256, 256, 0, stream>>>(sc, qb, pq);

  // k path: mixed_qk never materialized.
  // k_score = (k @ (pq .* Wka) + bka)*scale + mask ; pooled_k = pq .* pool(kw, k)
  k_score<1><<<dim3(128, 8), 256, 0, stream>>>(kb, Wka, bka, mask, pq, sc, 0.125f);
  k_softmax<<<128, 256, 0, stream>>>(sc);
  hipMemsetAsync(pk, 0, 32768, stream);
  k_pool<<<256, 256, 0, stream>>>(sc, kb, pk);

  // weighted = q .* (pk_raw .* pq), then out = weighted @ Wt + bt + q
  u16* wtd = xb;  // reuse
  k_weighted<<<2048, 256, 0, stream>>>(qb, pk, pq, wtd);
  k_gemm<2><<<2048, 256, 0, stream>>>(wtd, Wtt, bt, nullptr, qb, out, nullptr, nullptr, 8);
}

// Round 3
// 599.839 us; speedup vs baseline: 1.2981x; 1.0169x over previous
//
#include <hip/hip_runtime.h>

// ---------------------------------------------------------------------------
// FastSelfAttention on MI355X (gfx950), round 3.
// B=8, S=4096, D=1024, H=16, DH=64.
// New: 256x256 8-phase counted-vmcnt GEMM (T2+T3+T4+T5), k_weighted folded
// into per-batch output weights (k_wbt).
// ---------------------------------------------------------------------------

typedef unsigned short u16;
typedef float f32x4 __attribute__((ext_vector_type(4)));
typedef short bf16x8 __attribute__((ext_vector_type(8)));

#define DEV __device__ __forceinline__

DEV u16 f2bf(float f) {
  union { float f; unsigned u; } c; c.f = f;
  return (u16)((c.u + 0x7FFFu + ((c.u >> 16) & 1u)) >> 16);
}
DEV float bf2f(u16 h) {
  union { unsigned u; float f; } c; c.u = ((unsigned)h) << 16;
  return c.f;
}

#define SBAR_  do { __builtin_amdgcn_s_barrier(); __builtin_amdgcn_sched_barrier(0); } while (0)
#define LGKM0_ do { asm volatile("s_waitcnt lgkmcnt(0)" ::: "memory"); __builtin_amdgcn_sched_barrier(0); } while (0)

// --- f32 -> bf16 bulk convert ----------------------------------------------
__global__ __launch_bounds__(256) void k_cvt(const float* __restrict__ in,
                                             u16* __restrict__ out, int n4) {
  int i = blockIdx.x * 256 + threadIdx.x;
  const int stride = gridDim.x * 256;
  for (; i < n4; i += stride) {
    float4 v = reinterpret_cast<const float4*>(in)[i];
    ushort4 o;
    o.x = f2bf(v.x); o.y = f2bf(v.y); o.z = f2bf(v.z); o.w = f2bf(v.w);
    reinterpret_cast<ushort4*>(out)[i] = o;
  }
}

// --- W (K,N) f32 -> W^T (N,K) bf16 -----------------------------------------
__global__ __launch_bounds__(256) void k_transw(const float* __restrict__ W,
                                                u16* __restrict__ Wt) {
  __shared__ float tile[32][33];
  const int bn = blockIdx.x, bk = blockIdx.y;
  const int tx = threadIdx.x & 31, ty = threadIdx.x >> 5;
#pragma unroll
  for (int j = 0; j < 4; ++j)
    tile[ty + j * 8][tx] = W[(size_t)(bk * 32 + ty + j * 8) * 1024 + bn * 32 + tx];
  __syncthreads();
#pragma unroll
  for (int j = 0; j < 4; ++j)
    Wt[(size_t)(bn * 32 + ty + j * 8) * 1024 + bk * 32 + tx] = f2bf(tile[tx][ty + j * 8]);
}

// --- Wbt[b][n][k] = bf16( Wtt[n][k] * pk[b][k] * pq[b][k] ) ----------------
__global__ __launch_bounds__(256) void k_wbt(const u16* __restrict__ Wtt,
                                             const float* __restrict__ pk,
                                             const float* __restrict__ pq,
                                             u16* __restrict__ Wbt) {
  const int i = blockIdx.x * 256 + threadIdx.x;  // 1048576 threads
  const int k0 = (i & 127) * 8;
  const int n  = (i >> 7) & 1023;
  const int b  = i >> 17;
  bf16x8 wv = *reinterpret_cast<const bf16x8*>(&Wtt[n * 1024 + k0]);
  bf16x8 o;
#pragma unroll
  for (int j = 0; j < 8; ++j) {
    const float p = pk[b * 1024 + k0 + j] * pq[b * 1024 + k0 + j];
    o[j] = (short)f2bf(bf2f((u16)wv[j]) * p);
  }
  *reinterpret_cast<bf16x8*>(&Wbt[(size_t)b * 1048576 + (size_t)n * 1024 + k0]) = o;
}

// --- 256x256 8-phase GEMM: C = A(Mx1024) x Bt(Nx1024)^T --------------------
// 512 threads = 8 waves (2M x 4N), BK=64, double-buffered 128 KiB LDS,
// XOR-swizzled slots, counted vmcnt(8), raw barriers + sched_barrier(0).
// EPI 0: bf16 out split C0 (col<1024, bias0) / C1 (col>=1024, bias1).
// EPI 2: f32 out = acc + bias0[col] + bf2f(extra[row,col]); Bt is per-batch
//        (Wbt + batch*1M), batch = row0>>12.
template <int EPI>
__global__ __launch_bounds__(512, 2) void k_gemm8(const u16* __restrict__ A,
                                                  const u16* __restrict__ Bt,
                                                  const float* __restrict__ bias0,
                                                  const float* __restrict__ bias1,
                                                  const u16* __restrict__ extra,
                                                  float* __restrict__ Cf,
                                                  u16* __restrict__ C0,
                                                  u16* __restrict__ C1,
                                                  int gcols) {
  __shared__ __align__(16) u16 lds[2 * 32768];  // [buf][A|B][256][64]
  const int tid = threadIdx.x;
  const int w = tid >> 6, lane = tid & 63;
  const int wm = w >> 2, wn = w & 3;

  // chunked XCD swizzle (nwg % 8 == 0)
  const int nwg = gridDim.x;
  const int swz = (blockIdx.x & 7) * (nwg >> 3) + (blockIdx.x >> 3);
  const int ci = swz % gcols, ri = swz / gcols;
  const int row0 = ri * 256, col0 = ci * 256;

  // staging addressing: dest row = half*128 + p*64 + (tid>>3), slot = tid&7;
  // source pre-swizzled so physical slot s holds logical slot s ^ (row&7).
  const int sr = tid >> 3;
  const int ls8 = ((tid & 7) ^ (sr & 7)) * 8;
  const u16* gA = A + (size_t)(row0 + sr) * 1024 + ls8;
  const u16* gB;
  if (EPI == 2) {
    gB = Bt + (size_t)(row0 >> 12) * 1048576 + (size_t)(col0 + sr) * 1024 + ls8;
  } else {
    gB = Bt + (size_t)(col0 + sr) * 1024 + ls8;
  }

  auto stage = [&](int buf, int mat, int half, int kt, const u16* g) {
#pragma unroll
    for (int p = 0; p < 2; ++p) {
      const u16* src = g + (size_t)(half * 128 + p * 64) * 1024 + kt;
      u16* dst = (u16*)&lds[buf * 32768 + mat * 16384 + half * 8192 + p * 4096 + w * 512];
      __builtin_amdgcn_global_load_lds(
          (const __attribute__((address_space(1))) void*)src,
          (__attribute__((address_space(3))) void*)dst, 16, 0, 0);
    }
  };

  f32x4 acc[8][4] = {};

  // prologue: stage tile 0 -> buf0, tile 1 -> buf1 (8 loads each)
#pragma unroll
  for (int tt = 0; tt < 2; ++tt) {
    stage(tt, 0, 0, tt * 64, gA);
    stage(tt, 0, 1, tt * 64, gA);
    stage(tt, 1, 0, tt * 64, gB);
    stage(tt, 1, 1, tt * 64, gB);
  }
  asm volatile("s_waitcnt vmcnt(8)" ::: "memory");  // tile0 landed
  SBAR_;

  const int lr15 = lane & 15, lhi = lane >> 4, lx = lane & 7;
  bf16x8 Af[4][2], B0f[2][2], B1f[2][2];

  int cur = 0;
  for (int t = 0; t < 16; ++t) {
    const u16* bA = &lds[cur * 32768];
    const u16* bB = bA + 16384;
    const int kt2 = (t + 2) * 64;
    const bool st = (t < 14);

    // ---- P0: ds_read A(mh=0), B(all 4 n); MFMA Q(0,0) ----
#pragma unroll
    for (int mi = 0; mi < 4; ++mi)
#pragma unroll
      for (int ks = 0; ks < 2; ++ks)
        Af[mi][ks] = *reinterpret_cast<const bf16x8*>(
            &bA[(wm * 128 + mi * 16 + lr15) * 64 + (((ks << 2) | lhi) ^ lx) * 8]);
#pragma unroll
    for (int ni = 0; ni < 2; ++ni)
#pragma unroll
      for (int ks = 0; ks < 2; ++ks) {
        B0f[ni][ks] = *reinterpret_cast<const bf16x8*>(
            &bB[(wn * 64 + ni * 16 + lr15) * 64 + (((ks << 2) | lhi) ^ lx) * 8]);
        B1f[ni][ks] = *reinterpret_cast<const bf16x8*>(
            &bB[(wn * 64 + (2 + ni) * 16 + lr15) * 64 + (((ks << 2) | lhi) ^ lx) * 8]);
      }
    SBAR_;
    LGKM0_;
    __builtin_amdgcn_s_setprio(1);
#pragma unroll
    for (int mi = 0; mi < 4; ++mi)
#pragma unroll
      for (int ni = 0; ni < 2; ++ni)
#pragma unroll
        for (int ks = 0; ks < 2; ++ks)
          acc[mi][ni] = __builtin_amdgcn_mfma_f32_16x16x32_bf16(
              Af[mi][ks], B0f[ni][ks], acc[mi][ni], 0, 0, 0);
    __builtin_amdgcn_s_setprio(0);
    SBAR_;

    // ---- P1: stage (t+2).B-half0; MFMA Q(0,1) ----
    if (st) stage(cur, 1, 0, kt2, gB);
    SBAR_;
    __builtin_amdgcn_s_setprio(1);
#pragma unroll
    for (int mi = 0; mi < 4; ++mi)
#pragma unroll
      for (int ni = 0; ni < 2; ++ni)
#pragma unroll
        for (int ks = 0; ks < 2; ++ks)
          acc[mi][2 + ni] = __builtin_amdgcn_mfma_f32_16x16x32_bf16(
              Af[mi][ks], B1f[ni][ks], acc[mi][2 + ni], 0, 0, 0);
    __builtin_amdgcn_s_setprio(0);
    SBAR_;

    // ---- P2: ds_read A(mh=1); stage (t+2).B-half1; MFMA Q(1,1) ----
#pragma unroll
    for (int mi = 0; mi < 4; ++mi)
#pragma unroll
      for (int ks = 0; ks < 2; ++ks)
        Af[mi][ks] = *reinterpret_cast<const bf16x8*>(
            &bA[(wm * 128 + 64 + mi * 16 + lr15) * 64 + (((ks << 2) | lhi) ^ lx) * 8]);
    if (st) stage(cur, 1, 1, kt2, gB);
    SBAR_;
    LGKM0_;
    __builtin_amdgcn_s_setprio(1);
#pragma unroll
    for (int mi = 0; mi < 4; ++mi)
#pragma unroll
      for (int ni = 0; ni < 2; ++ni)
#pragma unroll
        for (int ks = 0; ks < 2; ++ks)
          acc[4 + mi][2 + ni] = __builtin_amdgcn_mfma_f32_16x16x32_bf16(
              Af[mi][ks], B1f[ni][ks], acc[4 + mi][2 + ni], 0, 0, 0);
    __builtin_amdgcn_s_setprio(0);
    SBAR_;

    // ---- P3: stage (t+2).A-half0,1; MFMA Q(1,0); counted vmcnt ----
    if (st) { stage(cur, 0, 0, kt2, gA); stage(cur, 0, 1, kt2, gA); }
    SBAR_;
    __builtin_amdgcn_s_setprio(1);
#pragma unroll
    for (int mi = 0; mi < 4; ++mi)
#pragma unroll
      for (int ni = 0; ni < 2; ++ni)
#pragma unroll
        for (int ks = 0; ks < 2; ++ks)
          acc[4 + mi][ni] = __builtin_amdgcn_mfma_f32_16x16x32_bf16(
              Af[mi][ks], B0f[ni][ks], acc[4 + mi][ni], 0, 0, 0);
    __builtin_amdgcn_s_setprio(0);
    if (t < 14) {
      asm volatile("s_waitcnt vmcnt(8)" ::: "memory");  // tile t+1 fully landed
    } else if (t == 14) {
      asm volatile("s_waitcnt vmcnt(0)" ::: "memory");
    }
    __builtin_amdgcn_sched_barrier(0);
    SBAR_;

    cur ^= 1;
  }

  // epilogue: C/D layout col=lane&15, row=(lane>>4)*4+reg
#pragma unroll
  for (int n = 0; n < 4; ++n) {
    const int col = col0 + wn * 64 + n * 16 + lr15;
    const float bv = (EPI == 0) ? (col < 1024 ? bias0[col] : bias1[col - 1024])
                                : bias0[col];
#pragma unroll
    for (int m = 0; m < 8; ++m) {
      const int rb = row0 + wm * 128 + m * 16 + lhi * 4;
#pragma unroll
      for (int j = 0; j < 4; ++j) {
        const int row = rb + j;
        const float v = acc[m][n][j] + bv;
        if constexpr (EPI == 0) {
          if (col < 1024) C0[(size_t)row * 1024 + col] = f2bf(v);
          else            C1[(size_t)row * 1024 + col - 1024] = f2bf(v);
        } else {
          const size_t idx = (size_t)row * 1024 + col;
          Cf[idx] = v + bf2f(extra[idx]);
        }
      }
    }
  }
}

// --- score[b,h,s] = (X[b,s,:].Weff[:,h] + bias[h])*scale + mask[b,s] -------
template <int HAS_PQ>
__global__ __launch_bounds__(256) void k_score(const u16* __restrict__ X,
                                               const float* __restrict__ Wa,
                                               const float* __restrict__ bias,
                                               const float* __restrict__ mask,
                                               const float* __restrict__ pq,
                                               float* __restrict__ score,
                                               float scale) {
  __shared__ float waT[16][1024];  // [h][d]
  const int b = blockIdx.y;
  for (int t = threadIdx.x; t < 16384; t += 256) {
    const int d = t >> 4, h = t & 15;
    float wv = Wa[t];
    if (HAS_PQ) wv *= pq[b * 1024 + d];
    waT[h][d] = wv;
  }
  __syncthreads();
  const int w = threadIdx.x >> 6, l = threadIdx.x & 63;
  for (int g = blockIdx.x * 4 + w; g < 1024; g += gridDim.x * 4) {
    const size_t r0 = (size_t)b * 4096 + g * 4;
    float cur[64];  // idx = rr*16 + h
#pragma unroll
    for (int i = 0; i < 64; ++i) cur[i] = 0.f;
    for (int i = 0; i < 8; ++i) {
      const int d = i * 128 + l * 2;
      float xv[4][2];
#pragma unroll
      for (int rr = 0; rr < 4; ++rr) {
        ushort2 xq = *reinterpret_cast<const ushort2*>(&X[(r0 + rr) * 1024 + d]);
        xv[rr][0] = bf2f(xq.x); xv[rr][1] = bf2f(xq.y);
      }
#pragma unroll
      for (int h = 0; h < 16; ++h) {
        float2 wv = *reinterpret_cast<const float2*>(&waT[h][d]);
#pragma unroll
        for (int rr = 0; rr < 4; ++rr)
          cur[rr * 16 + h] += xv[rr][0] * wv.x + xv[rr][1] * wv.y;
      }
    }
#pragma unroll
    for (int s = 0; s < 6; ++s) {
      const int m = 1 << s;
      const int bit = (l >> s) & 1;
#pragma unroll
      for (int j = 0; j < (32 >> s); ++j) {
        const float mine = bit ? cur[2 * j + 1] : cur[2 * j];
        const float other = bit ? cur[2 * j] : cur[2 * j + 1];
        cur[j] = mine + __shfl_xor(other, m, 64);
      }
    }
    const int rr = l >> 4, h = l & 15;
    const int si = g * 4 + rr;
    score[((size_t)b * 16 + h) * 4096 + si] =
        (cur[0] + bias[h]) * scale + mask[b * 4096 + si];
  }
}

// --- softmax over S (in place), one block per (b,h) row --------------------
__global__ __launch_bounds__(256) void k_softmax(float* __restrict__ sc) {
  __shared__ float red[8];
  float* p = sc + (size_t)blockIdx.x * 4096;
  const int t = threadIdx.x, w = t >> 6, l = t & 63;
  float v[16];
  float mx = -3.0e38f;
#pragma unroll
  for (int i = 0; i < 16; ++i) { v[i] = p[t + i * 256]; mx = fmaxf(mx, v[i]); }
#pragma unroll
  for (int m = 1; m < 64; m <<= 1) mx = fmaxf(mx, __shfl_xor(mx, m, 64));
  if (l == 0) red[w] = mx;
  __syncthreads();
  mx = fmaxf(fmaxf(red[0], red[1]), fmaxf(red[2], red[3]));
  float sum = 0.f;
#pragma unroll
  for (int i = 0; i < 16; ++i) { v[i] = __expf(v[i] - mx); sum += v[i]; }
#pragma unroll
  for (int m = 1; m < 64; m <<= 1) sum += __shfl_xor(sum, m, 64);
  if (l == 0) red[4 + w] = sum;
  __syncthreads();
  const float inv = 1.f / (red[4] + red[5] + red[6] + red[7]);
#pragma unroll
  for (int i = 0; i < 16; ++i) p[t + i * 256] = v[i] * inv;
}

// --- pooled[b,d] = sum_s w[b, d>>6, s] * X[b,s,d]  (bf16 X, atomics) -------
__global__ __launch_bounds__(256) void k_pool(const float* __restrict__ wgt,
                                              const u16* __restrict__ X,
                                              float* __restrict__ pooled) {
  __shared__ float wl[16][132];
  const int b = blockIdx.x >> 5, c = blockIdx.x & 31;
  const int s0 = c * 128;
  for (int t = threadIdx.x; t < 2048; t += 256) {
    const int h = t >> 7, si = t & 127;
    wl[h][si] = wgt[((size_t)b * 16 + h) * 4096 + s0 + si];
  }
  __syncthreads();
  const int d0 = threadIdx.x * 4, h = threadIdx.x >> 4;
  float a0 = 0, a1 = 0, a2 = 0, a3 = 0;
  for (int si = 0; si < 128; ++si) {
    const float wv = wl[h][si];
    const size_t base = ((size_t)b * 4096 + s0 + si) * 1024 + d0;
    ushort4 xq = *reinterpret_cast<const ushort4*>(X + base);
    a0 += wv * bf2f(xq.x); a1 += wv * bf2f(xq.y);
    a2 += wv * bf2f(xq.z); a3 += wv * bf2f(xq.w);
  }
  atomicAdd(&pooled[b * 1024 + d0 + 0], a0);
  atomicAdd(&pooled[b * 1024 + d0 + 1], a1);
  atomicAdd(&pooled[b * 1024 + d0 + 2], a2);
  atomicAdd(&pooled[b * 1024 + d0 + 3], a3);
}

// ---------------------------------------------------------------------------
extern "C" void kernel_launch(void* const* d_in, const int* in_sizes, int n_in,
                              void* d_out, int out_size, void* d_ws, size_t ws_size,
                              hipStream_t stream) {
  (void)in_sizes; (void)n_in; (void)out_size; (void)ws_size;
  const float* x    = (const float*)d_in[0];
  const float* mask = (const float*)d_in[1];
  const float* Wq   = (const float*)d_in[2];
  const float* bq   = (const float*)d_in[3];
  const float* Wqa  = (const float*)d_in[4];
  const float* bqa  = (const float*)d_in[5];
  const float* Wk   = (const float*)d_in[6];
  const float* bk   = (const float*)d_in[7];
  const float* Wka  = (const float*)d_in[8];
  const float* bka  = (const float*)d_in[9];
  const float* Wt   = (const float*)d_in[10];
  const float* bt   = (const float*)d_in[11];
  float* out = (float*)d_out;
  char* ws = (char*)d_ws;

  size_t off = 0;
  auto take = [&](size_t b) { char* p = ws + off; off += (b + 255) & ~(size_t)255; return p; };
  u16*   xb    = (u16*)  take(67108864);   // x bf16
  u16*   qb    = (u16*)  take(67108864);   // q bf16
  u16*   kb    = (u16*)  take(67108864);   // k bf16
  u16*   Wqkt  = (u16*)  take(4194304);    // [Wq^T ; Wk^T] (2048 x 1024) bf16
  u16*   Wtt   = (u16*)  take(2097152);    // Wt^T bf16
  u16*   Wbt   = (u16*)  take(16777216);   // per-batch out weights (8x1024x1024)
  float* sc    = (float*)take(2097152);    // (B,H,S) scores
  float* pq    = (float*)take(32768);      // pooled_q (B,1024)
  float* pk    = (float*)take(32768);      // raw pooled_k (B,1024)

  // prep
  k_cvt<<<2048, 256, 0, stream>>>(x, xb, 8388608);
  k_transw<<<dim3(32, 32), 256, 0, stream>>>(Wq, Wqkt);
  k_transw<<<dim3(32, 32), 256, 0, stream>>>(Wk, Wqkt + 1024 * 1024);
  k_transw<<<dim3(32, 32), 256, 0, stream>>>(Wt, Wtt);

  // fused q,k = x @ [Wq|Wk] + [bq|bk]   (128 row-tiles x 8 col-tiles)
  k_gemm8<0><<<1024, 512, 0, stream>>>(xb, Wqkt, bq, bk, nullptr, nullptr, qb, kb, 8);

  // q path
  k_score<0><<<dim3(128, 8), 256, 0, stream>>>(qb, Wqa, bqa, mask, nullptr, sc, 0.125f);
  k_softmax<<<128, 256, 0, stream>>>(sc);
  hipMemsetAsync(pq, 0, 32768, stream);
  k_pool<<<256, 256, 0, stream>>>(sc, qb, pq);

  // k path (mixed_qk factored out)
  k_score<1><<<dim3(128, 8), 256, 0, stream>>>(kb, Wka, bka, mask, pq, sc, 0.125f);
  k_softmax<<<128, 256, 0, stream>>>(sc);
  hipMemsetAsync(pk, 0, 32768, stream);
  k_pool<<<256, 256, 0, stream>>>(sc, kb, pk);

  // out = (q .* pk .* pq) @ Wt + bt + q  ==  q @ W_b + bt + q,
  // W_b = diag(pk.*pq) @ Wt per batch (row-tiles never straddle batches)
  k_wbt<<<4096, 256, 0, stream>>>(Wtt, pk, pq, Wbt);
  k_gemm8<2><<<512, 512, 0, stream>>>(qb, Wbt, bt, nullptr, qb, out, nullptr, nullptr, 4);
}

// Round 4
// 540.792 us; speedup vs baseline: 1.4398x; 1.1092x over previous
//
#include <hip/hip_runtime.h>

// ---------------------------------------------------------------------------
// FastSelfAttention on MI355X (gfx950), round 4.
// B=8, S=4096, D=1024, H=16, DH=64.
// R4: balanced 4-phase/K-tile schedule (reads 12/4/8/0, stages 0/0/4/4),
// minimal scheduling fences, LDS-staged coalesced epilogues (kills the 2.4x
// HBM write amplification of scattered bf16 stores).
// ---------------------------------------------------------------------------

typedef unsigned short u16;
typedef float f32x4 __attribute__((ext_vector_type(4)));
typedef short bf16x8 __attribute__((ext_vector_type(8)));

#define DEV __device__ __forceinline__

DEV u16 f2bf(float f) {
  union { float f; unsigned u; } c; c.f = f;
  return (u16)((c.u + 0x7FFFu + ((c.u >> 16) & 1u)) >> 16);
}
DEV float bf2f(u16 h) {
  union { unsigned u; float f; } c; c.u = ((unsigned)h) << 16;
  return c.f;
}

#define SBAR_  __builtin_amdgcn_s_barrier()
#define SB0_   __builtin_amdgcn_sched_barrier(0)
// rule #18: sched_barrier(0) after inline-asm lgkmcnt(0) so MFMA can't hoist
#define LGKM0_ do { asm volatile("s_waitcnt lgkmcnt(0)" ::: "memory"); SB0_; } while (0)

// --- f32 -> bf16 bulk convert ----------------------------------------------
__global__ __launch_bounds__(256) void k_cvt(const float* __restrict__ in,
                                             u16* __restrict__ out, int n4) {
  int i = blockIdx.x * 256 + threadIdx.x;
  const int stride = gridDim.x * 256;
  for (; i < n4; i += stride) {
    float4 v = reinterpret_cast<const float4*>(in)[i];
    ushort4 o;
    o.x = f2bf(v.x); o.y = f2bf(v.y); o.z = f2bf(v.z); o.w = f2bf(v.w);
    reinterpret_cast<ushort4*>(out)[i] = o;
  }
}

// --- W (K,N) f32 -> W^T (N,K) bf16 -----------------------------------------
__global__ __launch_bounds__(256) void k_transw(const float* __restrict__ W,
                                                u16* __restrict__ Wt) {
  __shared__ float tile[32][33];
  const int bn = blockIdx.x, bk = blockIdx.y;
  const int tx = threadIdx.x & 31, ty = threadIdx.x >> 5;
#pragma unroll
  for (int j = 0; j < 4; ++j)
    tile[ty + j * 8][tx] = W[(size_t)(bk * 32 + ty + j * 8) * 1024 + bn * 32 + tx];
  __syncthreads();
#pragma unroll
  for (int j = 0; j < 4; ++j)
    Wt[(size_t)(bn * 32 + ty + j * 8) * 1024 + bk * 32 + tx] = f2bf(tile[tx][ty + j * 8]);
}

// --- Wbt[b][n][k] = bf16( Wtt[n][k] * pk[b][k] * pq[b][k] ) ----------------
__global__ __launch_bounds__(256) void k_wbt(const u16* __restrict__ Wtt,
                                             const float* __restrict__ pk,
                                             const float* __restrict__ pq,
                                             u16* __restrict__ Wbt) {
  const int i = blockIdx.x * 256 + threadIdx.x;  // 1048576 threads
  const int k0 = (i & 127) * 8;
  const int n  = (i >> 7) & 1023;
  const int b  = i >> 17;
  bf16x8 wv = *reinterpret_cast<const bf16x8*>(&Wtt[n * 1024 + k0]);
  bf16x8 o;
#pragma unroll
  for (int j = 0; j < 8; ++j) {
    const float p = pk[b * 1024 + k0 + j] * pq[b * 1024 + k0 + j];
    o[j] = (short)f2bf(bf2f((u16)wv[j]) * p);
  }
  *reinterpret_cast<bf16x8*>(&Wbt[(size_t)b * 1048576 + (size_t)n * 1024 + k0]) = o;
}

// --- 256x256 GEMM, 4 phases/K-tile, LDS-staged epilogue --------------------
// C = A(Mx1024) x Bt(Nx1024)^T. 512 threads = 8 waves (2M x 4N), BK=64,
// double-buffered 128 KiB XOR-swizzled LDS, counted vmcnt(8).
// EPI 0: bf16 out; whole block's cols land in C0 (ci<gcols/2, bias0) or C1.
// EPI 2: f32 out = acc + bias0[col] + bf2f(extra[row,col]); Bt per-batch.
template <int EPI>
__global__ __launch_bounds__(512, 2) void k_gemm8(const u16* __restrict__ A,
                                                  const u16* __restrict__ Bt,
                                                  const float* __restrict__ bias0,
                                                  const float* __restrict__ bias1,
                                                  const u16* __restrict__ extra,
                                                  float* __restrict__ Cf,
                                                  u16* __restrict__ C0,
                                                  u16* __restrict__ C1,
                                                  int gcols) {
  __shared__ __align__(16) u16 lds[2 * 32768];  // [buf][A|B][256][64]
  const int tid = threadIdx.x;
  const int w = tid >> 6, lane = tid & 63;
  const int wm = w >> 2, wn = w & 3;

  // chunked XCD swizzle (nwg % 8 == 0)
  const int nwg = gridDim.x;
  const int swz = (blockIdx.x & 7) * (nwg >> 3) + (blockIdx.x >> 3);
  const int ci = swz % gcols, ri = swz / gcols;
  const int row0 = ri * 256, col0 = ci * 256;

  // staging: dest row = half*128 + p*64 + (tid>>3), slot = tid&7; source
  // pre-swizzled so physical slot s holds logical slot s ^ (row&7).
  const int sr = tid >> 3;
  const int ls8 = ((tid & 7) ^ (sr & 7)) * 8;
  const u16* gA = A + (size_t)(row0 + sr) * 1024 + ls8;
  const u16* gB;
  if (EPI == 2) {
    gB = Bt + (size_t)(row0 >> 12) * 1048576 + (size_t)(col0 + sr) * 1024 + ls8;
  } else {
    gB = Bt + (size_t)(col0 + sr) * 1024 + ls8;
  }

  auto stage = [&](int buf, int mat, int half, int kt, const u16* g) {
#pragma unroll
    for (int p = 0; p < 2; ++p) {
      const u16* src = g + (size_t)(half * 128 + p * 64) * 1024 + kt;
      u16* dst = (u16*)&lds[buf * 32768 + mat * 16384 + half * 8192 + p * 4096 + w * 512];
      __builtin_amdgcn_global_load_lds(
          (const __attribute__((address_space(1))) void*)src,
          (__attribute__((address_space(3))) void*)dst, 16, 0, 0);
    }
  };

  f32x4 acc[8][4] = {};

  // prologue: tile 0 -> buf0, tile 1 -> buf1
#pragma unroll
  for (int tt = 0; tt < 2; ++tt) {
    stage(tt, 0, 0, tt * 64, gA);
    stage(tt, 0, 1, tt * 64, gA);
    stage(tt, 1, 0, tt * 64, gB);
    stage(tt, 1, 1, tt * 64, gB);
  }
  asm volatile("s_waitcnt vmcnt(8)" ::: "memory");  // tile0 landed
  SBAR_;

  const int lr15 = lane & 15, lhi = lane >> 4, lx = lane & 7;
  bf16x8 Af[4][2], B0f[2][2], B1f[2][2];

  int cur = 0;
  for (int t = 0; t < 16; ++t) {
    const u16* bA = &lds[cur * 32768];
    const u16* bB = bA + 16384;
    const int kt2 = (t + 2) * 64;
    const bool st = (t < 14);

    // ---- P0: read A0 (8) + B0 (4); MFMA Q(0,0) ----
#pragma unroll
    for (int mi = 0; mi < 4; ++mi)
#pragma unroll
      for (int ks = 0; ks < 2; ++ks)
        Af[mi][ks] = *reinterpret_cast<const bf16x8*>(
            &bA[(wm * 128 + mi * 16 + lr15) * 64 + (((ks << 2) | lhi) ^ lx) * 8]);
#pragma unroll
    for (int ni = 0; ni < 2; ++ni)
#pragma unroll
      for (int ks = 0; ks < 2; ++ks)
        B0f[ni][ks] = *reinterpret_cast<const bf16x8*>(
            &bB[(wn * 64 + ni * 16 + lr15) * 64 + (((ks << 2) | lhi) ^ lx) * 8]);
    SBAR_;
    LGKM0_;
    __builtin_amdgcn_s_setprio(1);
#pragma unroll
    for (int mi = 0; mi < 4; ++mi)
#pragma unroll
      for (int ni = 0; ni < 2; ++ni)
#pragma unroll
        for (int ks = 0; ks < 2; ++ks)
          acc[mi][ni] = __builtin_amdgcn_mfma_f32_16x16x32_bf16(
              Af[mi][ks], B0f[ni][ks], acc[mi][ni], 0, 0, 0);
    __builtin_amdgcn_s_setprio(0);
    SBAR_;

    // ---- P1: read B1 (4); MFMA Q(0,1) ----
#pragma unroll
    for (int ni = 0; ni < 2; ++ni)
#pragma unroll
      for (int ks = 0; ks < 2; ++ks)
        B1f[ni][ks] = *reinterpret_cast<const bf16x8*>(
            &bB[(wn * 64 + (2 + ni) * 16 + lr15) * 64 + (((ks << 2) | lhi) ^ lx) * 8]);
    SBAR_;
    LGKM0_;
    __builtin_amdgcn_s_setprio(1);
#pragma unroll
    for (int mi = 0; mi < 4; ++mi)
#pragma unroll
      for (int ni = 0; ni < 2; ++ni)
#pragma unroll
        for (int ks = 0; ks < 2; ++ks)
          acc[mi][2 + ni] = __builtin_amdgcn_mfma_f32_16x16x32_bf16(
              Af[mi][ks], B1f[ni][ks], acc[mi][2 + ni], 0, 0, 0);
    __builtin_amdgcn_s_setprio(0);
    SBAR_;
    SB0_;  // keep P2's stage from hoisting above this barrier

    // ---- P2: read A1 (8); stage (t+2).B; MFMA Q(1,1) ----
#pragma unroll
    for (int mi = 0; mi < 4; ++mi)
#pragma unroll
      for (int ks = 0; ks < 2; ++ks)
        Af[mi][ks] = *reinterpret_cast<const bf16x8*>(
            &bA[(wm * 128 + 64 + mi * 16 + lr15) * 64 + (((ks << 2) | lhi) ^ lx) * 8]);
    if (st) { stage(cur, 1, 0, kt2, gB); stage(cur, 1, 1, kt2, gB); }
    SBAR_;
    LGKM0_;
    __builtin_amdgcn_s_setprio(1);
#pragma unroll
    for (int mi = 0; mi < 4; ++mi)
#pragma unroll
      for (int ni = 0; ni < 2; ++ni)
#pragma unroll
        for (int ks = 0; ks < 2; ++ks)
          acc[4 + mi][2 + ni] = __builtin_amdgcn_mfma_f32_16x16x32_bf16(
              Af[mi][ks], B1f[ni][ks], acc[4 + mi][2 + ni], 0, 0, 0);
    __builtin_amdgcn_s_setprio(0);
    SBAR_;
    SB0_;  // keep P3's stage from hoisting above this barrier

    // ---- P3: stage (t+2).A; MFMA Q(1,0); counted vmcnt; tile barrier ----
    if (st) { stage(cur, 0, 0, kt2, gA); stage(cur, 0, 1, kt2, gA); }
    __builtin_amdgcn_s_setprio(1);
#pragma unroll
    for (int mi = 0; mi < 4; ++mi)
#pragma unroll
      for (int ni = 0; ni < 2; ++ni)
#pragma unroll
        for (int ks = 0; ks < 2; ++ks)
          acc[4 + mi][ni] = __builtin_amdgcn_mfma_f32_16x16x32_bf16(
              Af[mi][ks], B0f[ni][ks], acc[4 + mi][ni], 0, 0, 0);
    __builtin_amdgcn_s_setprio(0);
    if (t < 14) {
      asm volatile("s_waitcnt vmcnt(8)" ::: "memory");  // tile t+1 landed
    } else if (t == 14) {
      asm volatile("s_waitcnt vmcnt(0)" ::: "memory");
    }
    SBAR_;

    cur ^= 1;
  }

  // ---- epilogue: LDS-staged coalesced stores ----
  // acc layout: col = col0 + wn*64 + n*16 + (lane&15); row = row0 + wm*128 +
  // m*16 + (lane>>4)*4 + j.
  if constexpr (EPI == 0) {
    // whole 256x256 bf16 tile fits in 128 KiB LDS
    u16* cl = (u16*)lds;
    const bool lo = (ci < (gcols >> 1));
    const float* bias = lo ? bias0 : bias1;
    u16* dst = lo ? C0 : C1;
    const int colloc0 = col0 - (lo ? 0 : 1024);
#pragma unroll
    for (int n = 0; n < 4; ++n) {
      const int cc = wn * 64 + n * 16 + lr15;
      const float bv = bias[colloc0 + cc];
#pragma unroll
      for (int m = 0; m < 8; ++m) {
        const int rb = wm * 128 + m * 16 + lhi * 4;
#pragma unroll
        for (int j = 0; j < 4; ++j) {
          const int r = rb + j;
          cl[r * 256 + (cc ^ ((r & 12) << 2))] = f2bf(acc[m][n][j] + bv);
        }
      }
    }
    __syncthreads();
#pragma unroll
    for (int pass = 0; pass < 16; ++pass) {
      const int idx = pass * 512 + tid;
      const int r = idx >> 5, g = idx & 31;  // 256 rows x 32 groups of 8 u16
      bf16x8 v = *reinterpret_cast<const bf16x8*>(
          &cl[r * 256 + ((g * 8) ^ ((r & 12) << 2))]);
      *reinterpret_cast<bf16x8*>(
          &dst[(size_t)(row0 + r) * 1024 + colloc0 + g * 8]) = v;
    }
  } else {
    // f32: two half-tiles (128 rows x 256 cols x 4B = 128 KiB each)
    float* clf = (float*)lds;
#pragma unroll
    for (int half = 0; half < 2; ++half) {
      __syncthreads();
      if (wm == half) {
#pragma unroll
        for (int n = 0; n < 4; ++n) {
          const int cc = wn * 64 + n * 16 + lr15;
#pragma unroll
          for (int m = 0; m < 8; ++m) {
            const int rb = m * 16 + lhi * 4;
#pragma unroll
            for (int j = 0; j < 4; ++j) {
              const int r = rb + j;
              clf[r * 256 + (cc ^ ((r & 12) << 2))] = acc[m][n][j];
            }
          }
        }
      }
      __syncthreads();
#pragma unroll
      for (int pass = 0; pass < 16; ++pass) {
        const int idx = pass * 512 + tid;
        const int r = idx >> 6, g = idx & 63;  // 128 rows x 64 groups of 4 f32
        f32x4 v = *reinterpret_cast<const f32x4*>(
            &clf[r * 256 + ((g * 4) ^ ((r & 12) << 2))]);
        const int grow = row0 + half * 128 + r;
        const int gcol = col0 + g * 4;
        ushort4 e = *reinterpret_cast<const ushort4*>(
            &extra[(size_t)grow * 1024 + gcol]);
        float4 o;
        o.x = v[0] + bias0[gcol + 0] + bf2f(e.x);
        o.y = v[1] + bias0[gcol + 1] + bf2f(e.y);
        o.z = v[2] + bias0[gcol + 2] + bf2f(e.z);
        o.w = v[3] + bias0[gcol + 3] + bf2f(e.w);
        *reinterpret_cast<float4*>(&Cf[(size_t)grow * 1024 + gcol]) = o;
      }
    }
  }
}

// --- score[b,h,s] = (X[b,s,:].Weff[:,h] + bias[h])*scale + mask[b,s] -------
template <int HAS_PQ>
__global__ __launch_bounds__(256) void k_score(const u16* __restrict__ X,
                                               const float* __restrict__ Wa,
                                               const float* __restrict__ bias,
                                               const float* __restrict__ mask,
                                               const float* __restrict__ pq,
                                               float* __restrict__ score,
                                               float scale) {
  __shared__ float waT[16][1024];  // [h][d]
  const int b = blockIdx.y;
  for (int t = threadIdx.x; t < 16384; t += 256) {
    const int d = t >> 4, h = t & 15;
    float wv = Wa[t];
    if (HAS_PQ) wv *= pq[b * 1024 + d];
    waT[h][d] = wv;
  }
  __syncthreads();
  const int w = threadIdx.x >> 6, l = threadIdx.x & 63;
  for (int g = blockIdx.x * 4 + w; g < 1024; g += gridDim.x * 4) {
    const size_t r0 = (size_t)b * 4096 + g * 4;
    float cur[64];  // idx = rr*16 + h
#pragma unroll
    for (int i = 0; i < 64; ++i) cur[i] = 0.f;
    for (int i = 0; i < 8; ++i) {
      const int d = i * 128 + l * 2;
      float xv[4][2];
#pragma unroll
      for (int rr = 0; rr < 4; ++rr) {
        ushort2 xq = *reinterpret_cast<const ushort2*>(&X[(r0 + rr) * 1024 + d]);
        xv[rr][0] = bf2f(xq.x); xv[rr][1] = bf2f(xq.y);
      }
#pragma unroll
      for (int h = 0; h < 16; ++h) {
        float2 wv = *reinterpret_cast<const float2*>(&waT[h][d]);
#pragma unroll
        for (int rr = 0; rr < 4; ++rr)
          cur[rr * 16 + h] += xv[rr][0] * wv.x + xv[rr][1] * wv.y;
      }
    }
#pragma unroll
    for (int s = 0; s < 6; ++s) {
      const int m = 1 << s;
      const int bit = (l >> s) & 1;
#pragma unroll
      for (int j = 0; j < (32 >> s); ++j) {
        const float mine = bit ? cur[2 * j + 1] : cur[2 * j];
        const float other = bit ? cur[2 * j] : cur[2 * j + 1];
        cur[j] = mine + __shfl_xor(other, m, 64);
      }
    }
    const int rr = l >> 4, h = l & 15;
    const int si = g * 4 + rr;
    score[((size_t)b * 16 + h) * 4096 + si] =
        (cur[0] + bias[h]) * scale + mask[b * 4096 + si];
  }
}

// --- softmax over S (in place), one block per (b,h) row --------------------
__global__ __launch_bounds__(256) void k_softmax(float* __restrict__ sc) {
  __shared__ float red[8];
  float* p = sc + (size_t)blockIdx.x * 4096;
  const int t = threadIdx.x, w = t >> 6, l = t & 63;
  float v[16];
  float mx = -3.0e38f;
#pragma unroll
  for (int i = 0; i < 16; ++i) { v[i] = p[t + i * 256]; mx = fmaxf(mx, v[i]); }
#pragma unroll
  for (int m = 1; m < 64; m <<= 1) mx = fmaxf(mx, __shfl_xor(mx, m, 64));
  if (l == 0) red[w] = mx;
  __syncthreads();
  mx = fmaxf(fmaxf(red[0], red[1]), fmaxf(red[2], red[3]));
  float sum = 0.f;
#pragma unroll
  for (int i = 0; i < 16; ++i) { v[i] = __expf(v[i] - mx); sum += v[i]; }
#pragma unroll
  for (int m = 1; m < 64; m <<= 1) sum += __shfl_xor(sum, m, 64);
  if (l == 0) red[4 + w] = sum;
  __syncthreads();
  const float inv = 1.f / (red[4] + red[5] + red[6] + red[7]);
#pragma unroll
  for (int i = 0; i < 16; ++i) p[t + i * 256] = v[i] * inv;
}

// --- pooled[b,d] = sum_s w[b, d>>6, s] * X[b,s,d]  (bf16 X, atomics) -------
__global__ __launch_bounds__(256) void k_pool(const float* __restrict__ wgt,
                                              const u16* __restrict__ X,
                                              float* __restrict__ pooled) {
  __shared__ float wl[16][132];
  const int b = blockIdx.x >> 5, c = blockIdx.x & 31;
  const int s0 = c * 128;
  for (int t = threadIdx.x; t < 2048; t += 256) {
    const int h = t >> 7, si = t & 127;
    wl[h][si] = wgt[((size_t)b * 16 + h) * 4096 + s0 + si];
  }
  __syncthreads();
  const int d0 = threadIdx.x * 4, h = threadIdx.x >> 4;
  float a0 = 0, a1 = 0, a2 = 0, a3 = 0;
  for (int si = 0; si < 128; ++si) {
    const float wv = wl[h][si];
    const size_t base = ((size_t)b * 4096 + s0 + si) * 1024 + d0;
    ushort4 xq = *reinterpret_cast<const ushort4*>(X + base);
    a0 += wv * bf2f(xq.x); a1 += wv * bf2f(xq.y);
    a2 += wv * bf2f(xq.z); a3 += wv * bf2f(xq.w);
  }
  atomicAdd(&pooled[b * 1024 + d0 + 0], a0);
  atomicAdd(&pooled[b * 1024 + d0 + 1], a1);
  atomicAdd(&pooled[b * 1024 + d0 + 2], a2);
  atomicAdd(&pooled[b * 1024 + d0 + 3], a3);
}

// ---------------------------------------------------------------------------
extern "C" void kernel_launch(void* const* d_in, const int* in_sizes, int n_in,
                              void* d_out, int out_size, void* d_ws, size_t ws_size,
                              hipStream_t stream) {
  (void)in_sizes; (void)n_in; (void)out_size; (void)ws_size;
  const float* x    = (const float*)d_in[0];
  const float* mask = (const float*)d_in[1];
  const float* Wq   = (const float*)d_in[2];
  const float* bq   = (const float*)d_in[3];
  const float* Wqa  = (const float*)d_in[4];
  const float* bqa  = (const float*)d_in[5];
  const float* Wk   = (const float*)d_in[6];
  const float* bk   = (const float*)d_in[7];
  const float* Wka  = (const float*)d_in[8];
  const float* bka  = (const float*)d_in[9];
  const float* Wt   = (const float*)d_in[10];
  const float* bt   = (const float*)d_in[11];
  float* out = (float*)d_out;
  char* ws = (char*)d_ws;

  size_t off = 0;
  auto take = [&](size_t b) { char* p = ws + off; off += (b + 255) & ~(size_t)255; return p; };
  u16*   xb    = (u16*)  take(67108864);   // x bf16
  u16*   qb    = (u16*)  take(67108864);   // q bf16
  u16*   kb    = (u16*)  take(67108864);   // k bf16
  u16*   Wqkt  = (u16*)  take(4194304);    // [Wq^T ; Wk^T] (2048 x 1024) bf16
  u16*   Wtt   = (u16*)  take(2097152);    // Wt^T bf16
  u16*   Wbt   = (u16*)  take(16777216);   // per-batch out weights (8x1024x1024)
  float* sc    = (float*)take(2097152);    // (B,H,S) scores
  float* pq    = (float*)take(32768);      // pooled_q (B,1024)
  float* pk    = (float*)take(32768);      // raw pooled_k (B,1024)

  // prep
  k_cvt<<<2048, 256, 0, stream>>>(x, xb, 8388608);
  k_transw<<<dim3(32, 32), 256, 0, stream>>>(Wq, Wqkt);
  k_transw<<<dim3(32, 32), 256, 0, stream>>>(Wk, Wqkt + 1024 * 1024);
  k_transw<<<dim3(32, 32), 256, 0, stream>>>(Wt, Wtt);

  // fused q,k = x @ [Wq|Wk] + [bq|bk]   (128 row-tiles x 8 col-tiles)
  k_gemm8<0><<<1024, 512, 0, stream>>>(xb, Wqkt, bq, bk, nullptr, nullptr, qb, kb, 8);

  // q path
  k_score<0><<<dim3(128, 8), 256, 0, stream>>>(qb, Wqa, bqa, mask, nullptr, sc, 0.125f);
  k_softmax<<<128, 256, 0, stream>>>(sc);
  hipMemsetAsync(pq, 0, 32768, stream);
  k_pool<<<256, 256, 0, stream>>>(sc, qb, pq);

  // k path (mixed_qk factored out)
  k_score<1><<<dim3(128, 8), 256, 0, stream>>>(kb, Wka, bka, mask, pq, sc, 0.125f);
  k_softmax<<<128, 256, 0, stream>>>(sc);
  hipMemsetAsync(pk, 0, 32768, stream);
  k_pool<<<256, 256, 0, stream>>>(sc, kb, pk);

  // out = (q .* pk .* pq) @ Wt + bt + q  ==  q @ W_b + bt + q
  k_wbt<<<4096, 256, 0, stream>>>(Wtt, pk, pq, Wbt);
  k_gemm8<2><<<512, 512, 0, stream>>>(qb, Wbt, bt, nullptr, qb, out, nullptr, nullptr, 4);
}

// Round 5
// 535.548 us; speedup vs baseline: 1.4539x; 1.0098x over previous
//
#include <hip/hip_runtime.h>

// ---------------------------------------------------------------------------
// FastSelfAttention on MI355X (gfx950), round 5.
// B=8, S=4096, D=1024, H=16, DH=64.
// R5: GEMM K-loop restructured to 2 barriers/K-tile with compiler-counted
// lgkm waits (reads issue early, MFMAs start per-operand) -> LDS pipe and
// MFMA pipe overlap across desynced waves. Epilogues unchanged (R4).
// ---------------------------------------------------------------------------

typedef unsigned short u16;
typedef float f32x4 __attribute__((ext_vector_type(4)));
typedef short bf16x8 __attribute__((ext_vector_type(8)));

#define DEV __device__ __forceinline__

DEV u16 f2bf(float f) {
  union { float f; unsigned u; } c; c.f = f;
  return (u16)((c.u + 0x7FFFu + ((c.u >> 16) & 1u)) >> 16);
}
DEV float bf2f(u16 h) {
  union { unsigned u; float f; } c; c.u = ((unsigned)h) << 16;
  return c.f;
}

#define SBAR_  __builtin_amdgcn_s_barrier()
#define SB0_   __builtin_amdgcn_sched_barrier(0)
// rule #18: sched_barrier(0) after inline-asm lgkmcnt(0) so MFMA can't hoist
#define LGKM0_ do { asm volatile("s_waitcnt lgkmcnt(0)" ::: "memory"); SB0_; } while (0)

// --- f32 -> bf16 bulk convert ----------------------------------------------
__global__ __launch_bounds__(256) void k_cvt(const float* __restrict__ in,
                                             u16* __restrict__ out, int n4) {
  int i = blockIdx.x * 256 + threadIdx.x;
  const int stride = gridDim.x * 256;
  for (; i < n4; i += stride) {
    float4 v = reinterpret_cast<const float4*>(in)[i];
    ushort4 o;
    o.x = f2bf(v.x); o.y = f2bf(v.y); o.z = f2bf(v.z); o.w = f2bf(v.w);
    reinterpret_cast<ushort4*>(out)[i] = o;
  }
}

// --- W (K,N) f32 -> W^T (N,K) bf16 -----------------------------------------
__global__ __launch_bounds__(256) void k_transw(const float* __restrict__ W,
                                                u16* __restrict__ Wt) {
  __shared__ float tile[32][33];
  const int bn = blockIdx.x, bk = blockIdx.y;
  const int tx = threadIdx.x & 31, ty = threadIdx.x >> 5;
#pragma unroll
  for (int j = 0; j < 4; ++j)
    tile[ty + j * 8][tx] = W[(size_t)(bk * 32 + ty + j * 8) * 1024 + bn * 32 + tx];
  __syncthreads();
#pragma unroll
  for (int j = 0; j < 4; ++j)
    Wt[(size_t)(bn * 32 + ty + j * 8) * 1024 + bk * 32 + tx] = f2bf(tile[tx][ty + j * 8]);
}

// --- Wbt[b][n][k] = bf16( Wtt[n][k] * pk[b][k] * pq[b][k] ) ----------------
__global__ __launch_bounds__(256) void k_wbt(const u16* __restrict__ Wtt,
                                             const float* __restrict__ pk,
                                             const float* __restrict__ pq,
                                             u16* __restrict__ Wbt) {
  const int i = blockIdx.x * 256 + threadIdx.x;  // 1048576 threads
  const int k0 = (i & 127) * 8;
  const int n  = (i >> 7) & 1023;
  const int b  = i >> 17;
  bf16x8 wv = *reinterpret_cast<const bf16x8*>(&Wtt[n * 1024 + k0]);
  bf16x8 o;
#pragma unroll
  for (int j = 0; j < 8; ++j) {
    const float p = pk[b * 1024 + k0 + j] * pq[b * 1024 + k0 + j];
    o[j] = (short)f2bf(bf2f((u16)wv[j]) * p);
  }
  *reinterpret_cast<bf16x8*>(&Wbt[(size_t)b * 1048576 + (size_t)n * 1024 + k0]) = o;
}

// --- 256x256 GEMM, 2 barriers/K-tile, LDS-staged epilogue ------------------
// C = A(Mx1024) x Bt(Nx1024)^T. 512 threads = 8 waves (2M x 4N), BK=64,
// double-buffered 128 KiB XOR-swizzled LDS, counted vmcnt(8), compiler-
// counted lgkm waits inside the tile.
// EPI 0: bf16 out; whole block's cols land in C0 (ci<gcols/2, bias0) or C1.
// EPI 2: f32 out = acc + bias0[col] + bf2f(extra[row,col]); Bt per-batch.
template <int EPI>
__global__ __launch_bounds__(512, 2) void k_gemm8(const u16* __restrict__ A,
                                                  const u16* __restrict__ Bt,
                                                  const float* __restrict__ bias0,
                                                  const float* __restrict__ bias1,
                                                  const u16* __restrict__ extra,
                                                  float* __restrict__ Cf,
                                                  u16* __restrict__ C0,
                                                  u16* __restrict__ C1,
                                                  int gcols) {
  __shared__ __align__(16) u16 lds[2 * 32768];  // [buf][A|B][256][64]
  const int tid = threadIdx.x;
  const int w = tid >> 6, lane = tid & 63;
  const int wm = w >> 2, wn = w & 3;

  // chunked XCD swizzle (nwg % 8 == 0)
  const int nwg = gridDim.x;
  const int swz = (blockIdx.x & 7) * (nwg >> 3) + (blockIdx.x >> 3);
  const int ci = swz % gcols, ri = swz / gcols;
  const int row0 = ri * 256, col0 = ci * 256;

  // staging: dest row = half*128 + p*64 + (tid>>3), slot = tid&7; source
  // pre-swizzled so physical slot s holds logical slot s ^ (row&7).
  const int sr = tid >> 3;
  const int ls8 = ((tid & 7) ^ (sr & 7)) * 8;
  const u16* gA = A + (size_t)(row0 + sr) * 1024 + ls8;
  const u16* gB;
  if (EPI == 2) {
    gB = Bt + (size_t)(row0 >> 12) * 1048576 + (size_t)(col0 + sr) * 1024 + ls8;
  } else {
    gB = Bt + (size_t)(col0 + sr) * 1024 + ls8;
  }

  auto stage = [&](int buf, int mat, int half, int kt, const u16* g) {
#pragma unroll
    for (int p = 0; p < 2; ++p) {
      const u16* src = g + (size_t)(half * 128 + p * 64) * 1024 + kt;
      u16* dst = (u16*)&lds[buf * 32768 + mat * 16384 + half * 8192 + p * 4096 + w * 512];
      __builtin_amdgcn_global_load_lds(
          (const __attribute__((address_space(1))) void*)src,
          (__attribute__((address_space(3))) void*)dst, 16, 0, 0);
    }
  };

  f32x4 acc[8][4] = {};

  // prologue: tile 0 -> buf0, tile 1 -> buf1
#pragma unroll
  for (int tt = 0; tt < 2; ++tt) {
    stage(tt, 0, 0, tt * 64, gA);
    stage(tt, 0, 1, tt * 64, gA);
    stage(tt, 1, 0, tt * 64, gB);
    stage(tt, 1, 1, tt * 64, gB);
  }
  asm volatile("s_waitcnt vmcnt(8)" ::: "memory");  // tile0 landed
  SBAR_;

  const int lr15 = lane & 15, lhi = lane >> 4, lx = lane & 7;
  bf16x8 Af[4][2], B0f[2][2], B1f[2][2];

  int cur = 0;
  for (int t = 0; t < 16; ++t) {
    const u16* bA = &lds[cur * 32768];
    const u16* bB = bA + 16384;
    const int kt2 = (t + 2) * 64;
    const bool st = (t < 14);

    // issue reads: A0 (8) + B0 (4) + B1 (4); compiler inserts counted
    // lgkm waits per MFMA below -> per-wave reads overlap other waves' MFMAs
#pragma unroll
    for (int mi = 0; mi < 4; ++mi)
#pragma unroll
      for (int ks = 0; ks < 2; ++ks)
        Af[mi][ks] = *reinterpret_cast<const bf16x8*>(
            &bA[(wm * 128 + mi * 16 + lr15) * 64 + (((ks << 2) | lhi) ^ lx) * 8]);
#pragma unroll
    for (int ni = 0; ni < 2; ++ni)
#pragma unroll
      for (int ks = 0; ks < 2; ++ks) {
        B0f[ni][ks] = *reinterpret_cast<const bf16x8*>(
            &bB[(wn * 64 + ni * 16 + lr15) * 64 + (((ks << 2) | lhi) ^ lx) * 8]);
        B1f[ni][ks] = *reinterpret_cast<const bf16x8*>(
            &bB[(wn * 64 + (2 + ni) * 16 + lr15) * 64 + (((ks << 2) | lhi) ^ lx) * 8]);
      }
    SB0_;  // pin: all 16 reads issued above, MFMAs below

    __builtin_amdgcn_s_setprio(1);
#pragma unroll
    for (int mi = 0; mi < 4; ++mi)
#pragma unroll
      for (int ni = 0; ni < 2; ++ni)
#pragma unroll
        for (int ks = 0; ks < 2; ++ks)
          acc[mi][ni] = __builtin_amdgcn_mfma_f32_16x16x32_bf16(
              Af[mi][ks], B0f[ni][ks], acc[mi][ni], 0, 0, 0);
#pragma unroll
    for (int mi = 0; mi < 4; ++mi)
#pragma unroll
      for (int ni = 0; ni < 2; ++ni)
#pragma unroll
        for (int ks = 0; ks < 2; ++ks)
          acc[mi][2 + ni] = __builtin_amdgcn_mfma_f32_16x16x32_bf16(
              Af[mi][ks], B1f[ni][ks], acc[mi][2 + ni], 0, 0, 0);
    __builtin_amdgcn_s_setprio(0);

    // read A1 (8), reusing Af registers (A0 dead after Q01)
#pragma unroll
    for (int mi = 0; mi < 4; ++mi)
#pragma unroll
      for (int ks = 0; ks < 2; ++ks)
        Af[mi][ks] = *reinterpret_cast<const bf16x8*>(
            &bA[(wm * 128 + 64 + mi * 16 + lr15) * 64 + (((ks << 2) | lhi) ^ lx) * 8]);
    LGKM0_;  // all reads of cur complete (this wave)
    SBAR_;   // all waves done reading cur -> safe to overwrite
    SB0_;    // keep stages below the barrier

    if (st) {
      stage(cur, 1, 0, kt2, gB); stage(cur, 1, 1, kt2, gB);
      stage(cur, 0, 0, kt2, gA); stage(cur, 0, 1, kt2, gA);
    }

    __builtin_amdgcn_s_setprio(1);
#pragma unroll
    for (int mi = 0; mi < 4; ++mi)
#pragma unroll
      for (int ni = 0; ni < 2; ++ni)
#pragma unroll
        for (int ks = 0; ks < 2; ++ks)
          acc[4 + mi][2 + ni] = __builtin_amdgcn_mfma_f32_16x16x32_bf16(
              Af[mi][ks], B1f[ni][ks], acc[4 + mi][2 + ni], 0, 0, 0);
#pragma unroll
    for (int mi = 0; mi < 4; ++mi)
#pragma unroll
      for (int ni = 0; ni < 2; ++ni)
#pragma unroll
        for (int ks = 0; ks < 2; ++ks)
          acc[4 + mi][ni] = __builtin_amdgcn_mfma_f32_16x16x32_bf16(
              Af[mi][ks], B0f[ni][ks], acc[4 + mi][ni], 0, 0, 0);
    __builtin_amdgcn_s_setprio(0);

    if (t < 14) {
      asm volatile("s_waitcnt vmcnt(8)" ::: "memory");  // tile t+1 landed
    } else if (t == 14) {
      asm volatile("s_waitcnt vmcnt(0)" ::: "memory");
    }
    SB0_;
    SBAR_;  // next buffer valid for all waves

    cur ^= 1;
  }

  // ---- epilogue: LDS-staged coalesced stores (unchanged from R4) ----
  if constexpr (EPI == 0) {
    u16* cl = (u16*)lds;
    const bool lo = (ci < (gcols >> 1));
    const float* bias = lo ? bias0 : bias1;
    u16* dst = lo ? C0 : C1;
    const int colloc0 = col0 - (lo ? 0 : 1024);
#pragma unroll
    for (int n = 0; n < 4; ++n) {
      const int cc = wn * 64 + n * 16 + lr15;
      const float bv = bias[colloc0 + cc];
#pragma unroll
      for (int m = 0; m < 8; ++m) {
        const int rb = wm * 128 + m * 16 + lhi * 4;
#pragma unroll
        for (int j = 0; j < 4; ++j) {
          const int r = rb + j;
          cl[r * 256 + (cc ^ ((r & 12) << 2))] = f2bf(acc[m][n][j] + bv);
        }
      }
    }
    __syncthreads();
#pragma unroll
    for (int pass = 0; pass < 16; ++pass) {
      const int idx = pass * 512 + tid;
      const int r = idx >> 5, g = idx & 31;  // 256 rows x 32 groups of 8 u16
      bf16x8 v = *reinterpret_cast<const bf16x8*>(
          &cl[r * 256 + ((g * 8) ^ ((r & 12) << 2))]);
      *reinterpret_cast<bf16x8*>(
          &dst[(size_t)(row0 + r) * 1024 + colloc0 + g * 8]) = v;
    }
  } else {
    float* clf = (float*)lds;
#pragma unroll
    for (int half = 0; half < 2; ++half) {
      __syncthreads();
      if (wm == half) {
#pragma unroll
        for (int n = 0; n < 4; ++n) {
          const int cc = wn * 64 + n * 16 + lr15;
#pragma unroll
          for (int m = 0; m < 8; ++m) {
            const int rb = m * 16 + lhi * 4;
#pragma unroll
            for (int j = 0; j < 4; ++j) {
              const int r = rb + j;
              clf[r * 256 + (cc ^ ((r & 12) << 2))] = acc[m][n][j];
            }
          }
        }
      }
      __syncthreads();
#pragma unroll
      for (int pass = 0; pass < 16; ++pass) {
        const int idx = pass * 512 + tid;
        const int r = idx >> 6, g = idx & 63;  // 128 rows x 64 groups of 4 f32
        f32x4 v = *reinterpret_cast<const f32x4*>(
            &clf[r * 256 + ((g * 4) ^ ((r & 12) << 2))]);
        const int grow = row0 + half * 128 + r;
        const int gcol = col0 + g * 4;
        ushort4 e = *reinterpret_cast<const ushort4*>(
            &extra[(size_t)grow * 1024 + gcol]);
        float4 o;
        o.x = v[0] + bias0[gcol + 0] + bf2f(e.x);
        o.y = v[1] + bias0[gcol + 1] + bf2f(e.y);
        o.z = v[2] + bias0[gcol + 2] + bf2f(e.z);
        o.w = v[3] + bias0[gcol + 3] + bf2f(e.w);
        *reinterpret_cast<float4*>(&Cf[(size_t)grow * 1024 + gcol]) = o;
      }
    }
  }
}

// --- score[b,h,s] = (X[b,s,:].Weff[:,h] + bias[h])*scale + mask[b,s] -------
template <int HAS_PQ>
__global__ __launch_bounds__(256) void k_score(const u16* __restrict__ X,
                                               const float* __restrict__ Wa,
                                               const float* __restrict__ bias,
                                               const float* __restrict__ mask,
                                               const float* __restrict__ pq,
                                               float* __restrict__ score,
                                               float scale) {
  __shared__ float waT[16][1024];  // [h][d]
  const int b = blockIdx.y;
  for (int t = threadIdx.x; t < 16384; t += 256) {
    const int d = t >> 4, h = t & 15;
    float wv = Wa[t];
    if (HAS_PQ) wv *= pq[b * 1024 + d];
    waT[h][d] = wv;
  }
  __syncthreads();
  const int w = threadIdx.x >> 6, l = threadIdx.x & 63;
  for (int g = blockIdx.x * 4 + w; g < 1024; g += gridDim.x * 4) {
    const size_t r0 = (size_t)b * 4096 + g * 4;
    float cur[64];  // idx = rr*16 + h
#pragma unroll
    for (int i = 0; i < 64; ++i) cur[i] = 0.f;
    for (int i = 0; i < 8; ++i) {
      const int d = i * 128 + l * 2;
      float xv[4][2];
#pragma unroll
      for (int rr = 0; rr < 4; ++rr) {
        ushort2 xq = *reinterpret_cast<const ushort2*>(&X[(r0 + rr) * 1024 + d]);
        xv[rr][0] = bf2f(xq.x); xv[rr][1] = bf2f(xq.y);
      }
#pragma unroll
      for (int h = 0; h < 16; ++h) {
        float2 wv = *reinterpret_cast<const float2*>(&waT[h][d]);
#pragma unroll
        for (int rr = 0; rr < 4; ++rr)
          cur[rr * 16 + h] += xv[rr][0] * wv.x + xv[rr][1] * wv.y;
      }
    }
#pragma unroll
    for (int s = 0; s < 6; ++s) {
      const int m = 1 << s;
      const int bit = (l >> s) & 1;
#pragma unroll
      for (int j = 0; j < (32 >> s); ++j) {
        const float mine = bit ? cur[2 * j + 1] : cur[2 * j];
        const float other = bit ? cur[2 * j] : cur[2 * j + 1];
        cur[j] = mine + __shfl_xor(other, m, 64);
      }
    }
    const int rr = l >> 4, h = l & 15;
    const int si = g * 4 + rr;
    score[((size_t)b * 16 + h) * 4096 + si] =
        (cur[0] + bias[h]) * scale + mask[b * 4096 + si];
  }
}

// --- softmax over S (in place), one block per (b,h) row --------------------
__global__ __launch_bounds__(256) void k_softmax(float* __restrict__ sc) {
  __shared__ float red[8];
  float* p = sc + (size_t)blockIdx.x * 4096;
  const int t = threadIdx.x, w = t >> 6, l = t & 63;
  float v[16];
  float mx = -3.0e38f;
#pragma unroll
  for (int i = 0; i < 16; ++i) { v[i] = p[t + i * 256]; mx = fmaxf(mx, v[i]); }
#pragma unroll
  for (int m = 1; m < 64; m <<= 1) mx = fmaxf(mx, __shfl_xor(mx, m, 64));
  if (l == 0) red[w] = mx;
  __syncthreads();
  mx = fmaxf(fmaxf(red[0], red[1]), fmaxf(red[2], red[3]));
  float sum = 0.f;
#pragma unroll
  for (int i = 0; i < 16; ++i) { v[i] = __expf(v[i] - mx); sum += v[i]; }
#pragma unroll
  for (int m = 1; m < 64; m <<= 1) sum += __shfl_xor(sum, m, 64);
  if (l == 0) red[4 + w] = sum;
  __syncthreads();
  const float inv = 1.f / (red[4] + red[5] + red[6] + red[7]);
#pragma unroll
  for (int i = 0; i < 16; ++i) p[t + i * 256] = v[i] * inv;
}

// --- pooled[b,d] = sum_s w[b, d>>6, s] * X[b,s,d]  (bf16 X, atomics) -------
__global__ __launch_bounds__(256) void k_pool(const float* __restrict__ wgt,
                                              const u16* __restrict__ X,
                                              float* __restrict__ pooled) {
  __shared__ float wl[16][132];
  const int b = blockIdx.x >> 5, c = blockIdx.x & 31;
  const int s0 = c * 128;
  for (int t = threadIdx.x; t < 2048; t += 256) {
    const int h = t >> 7, si = t & 127;
    wl[h][si] = wgt[((size_t)b * 16 + h) * 4096 + s0 + si];
  }
  __syncthreads();
  const int d0 = threadIdx.x * 4, h = threadIdx.x >> 4;
  float a0 = 0, a1 = 0, a2 = 0, a3 = 0;
  for (int si = 0; si < 128; ++si) {
    const float wv = wl[h][si];
    const size_t base = ((size_t)b * 4096 + s0 + si) * 1024 + d0;
    ushort4 xq = *reinterpret_cast<const ushort4*>(X + base);
    a0 += wv * bf2f(xq.x); a1 += wv * bf2f(xq.y);
    a2 += wv * bf2f(xq.z); a3 += wv * bf2f(xq.w);
  }
  atomicAdd(&pooled[b * 1024 + d0 + 0], a0);
  atomicAdd(&pooled[b * 1024 + d0 + 1], a1);
  atomicAdd(&pooled[b * 1024 + d0 + 2], a2);
  atomicAdd(&pooled[b * 1024 + d0 + 3], a3);
}

// ---------------------------------------------------------------------------
extern "C" void kernel_launch(void* const* d_in, const int* in_sizes, int n_in,
                              void* d_out, int out_size, void* d_ws, size_t ws_size,
                              hipStream_t stream) {
  (void)in_sizes; (void)n_in; (void)out_size; (void)ws_size;
  const float* x    = (const float*)d_in[0];
  const float* mask = (const float*)d_in[1];
  const float* Wq   = (const float*)d_in[2];
  const float* bq   = (const float*)d_in[3];
  const float* Wqa  = (const float*)d_in[4];
  const float* bqa  = (const float*)d_in[5];
  const float* Wk   = (const float*)d_in[6];
  const float* bk   = (const float*)d_in[7];
  const float* Wka  = (const float*)d_in[8];
  const float* bka  = (const float*)d_in[9];
  const float* Wt   = (const float*)d_in[10];
  const float* bt   = (const float*)d_in[11];
  float* out = (float*)d_out;
  char* ws = (char*)d_ws;

  size_t off = 0;
  auto take = [&](size_t b) { char* p = ws + off; off += (b + 255) & ~(size_t)255; return p; };
  u16*   xb    = (u16*)  take(67108864);   // x bf16
  u16*   qb    = (u16*)  take(67108864);   // q bf16
  u16*   kb    = (u16*)  take(67108864);   // k bf16
  u16*   Wqkt  = (u16*)  take(4194304);    // [Wq^T ; Wk^T] (2048 x 1024) bf16
  u16*   Wtt   = (u16*)  take(2097152);    // Wt^T bf16
  u16*   Wbt   = (u16*)  take(16777216);   // per-batch out weights (8x1024x1024)
  float* sc    = (float*)take(2097152);    // (B,H,S) scores
  float* pq    = (float*)take(32768);      // pooled_q (B,1024)
  float* pk    = (float*)take(32768);      // raw pooled_k (B,1024)

  // prep
  k_cvt<<<2048, 256, 0, stream>>>(x, xb, 8388608);
  k_transw<<<dim3(32, 32), 256, 0, stream>>>(Wq, Wqkt);
  k_transw<<<dim3(32, 32), 256, 0, stream>>>(Wk, Wqkt + 1024 * 1024);
  k_transw<<<dim3(32, 32), 256, 0, stream>>>(Wt, Wtt);

  // fused q,k = x @ [Wq|Wk] + [bq|bk]   (128 row-tiles x 8 col-tiles)
  k_gemm8<0><<<1024, 512, 0, stream>>>(xb, Wqkt, bq, bk, nullptr, nullptr, qb, kb, 8);

  // q path
  k_score<0><<<dim3(128, 8), 256, 0, stream>>>(qb, Wqa, bqa, mask, nullptr, sc, 0.125f);
  k_softmax<<<128, 256, 0, stream>>>(sc);
  hipMemsetAsync(pq, 0, 32768, stream);
  k_pool<<<256, 256, 0, stream>>>(sc, qb, pq);

  // k path (mixed_qk factored out)
  k_score<1><<<dim3(128, 8), 256, 0, stream>>>(kb, Wka, bka, mask, pq, sc, 0.125f);
  k_softmax<<<128, 256, 0, stream>>>(sc);
  hipMemsetAsync(pk, 0, 32768, stream);
  k_pool<<<256, 256, 0, stream>>>(sc, kb, pk);

  // out = (q .* pk .* pq) @ Wt + bt + q  ==  q @ W_b + bt + q
  k_wbt<<<4096, 256, 0, stream>>>(Wtt, pk, pq, Wbt);
  k_gemm8<2><<<512, 512, 0, stream>>>(qb, Wbt, bt, nullptr, qb, out, nullptr, nullptr, 4);
}